// Round 4
// baseline (7442.489 us; speedup 1.0000x reference)
//
#include <hip/hip_runtime.h>

#define Bdim 640
#define Hdim 768
#define PJdim 256
#define Tdim 160
#define NSTEP (Tdim + 2)

typedef _Float16 half8 __attribute__((ext_vector_type(8)));
typedef float floatx4 __attribute__((ext_vector_type(4)));

// ---------------- workspace layout (halfs/bytes) ----------------
constexpr size_t HB_HALFS = 3ull * Bdim * PJdim;            // 491,520
constexpr size_t ZP_OFF   = HB_HALFS * 2;                   // byte offset
constexpr size_t MB_OFF   = ZP_OFF + 256;
constexpr size_t MB_HALFS = 3ull * Bdim * Hdim;             // 1,474,560
constexpr size_t X_OFF    = MB_OFF + MB_HALFS * 2;
constexpr size_t X_HALFS  = (size_t)Tdim * Bdim * 40;       // 4,096,000
constexpr size_t W_OFF    = X_OFF + X_HALFS * 2;
constexpr size_t W_HALFS  = 36ull * 131072;                 // 4,718,592
constexpr size_t P_OFF    = W_OFF + W_HALFS * 2;
constexpr size_t P_HALFS  = 3ull * 196608;                  // 589,824
constexpr size_t C_OFF    = P_OFF + P_HALFS * 2;
constexpr size_t C_BYTES  = 3ull * Bdim * Hdim * 4;

__device__ __forceinline__ float sigm(float v) { return 1.0f / (1.0f + __expf(-v)); }
__device__ __forceinline__ float tanh_fast(float v) { return 2.0f / (1.0f + __expf(-2.0f * v)) - 1.0f; }

// Device-coherent 2B store (bypass L1/L2, lands at coherence point).
// Used ONLY by cross-XCD h16 producer edges.
__device__ __forceinline__ void st_coh16b(void* p, _Float16 h) {
    union { _Float16 h; unsigned short u; } cv; cv.h = h;
    __hip_atomic_store((unsigned short*)p, cv.u, __ATOMIC_RELAXED, __HIP_MEMORY_SCOPE_AGENT);
}

// ---------------- fine-grained pipeline sync (R3 semantics, kept) ----------------
__device__ __forceinline__ void pipe_wait(unsigned* c0, unsigned t0, unsigned* c1, unsigned t1)
{
    if (threadIdx.x == 0) {
        if (t0)
            while (__hip_atomic_load(c0, __ATOMIC_RELAXED, __HIP_MEMORY_SCOPE_AGENT) < t0)
                __builtin_amdgcn_s_sleep(1);
        if (c1 && t1)
            while (__hip_atomic_load(c1, __ATOMIC_RELAXED, __HIP_MEMORY_SCOPE_AGENT) < t1)
                __builtin_amdgcn_s_sleep(1);
        __builtin_amdgcn_fence(__ATOMIC_ACQUIRE, "agent");   // inv only, no wbl2
    }
    __syncthreads();
}

__device__ __forceinline__ void pipe_sig(unsigned* c)
{
    __syncthreads();                // drains vmcnt: stores visible at shared L2 / LLC
    if (threadIdx.x == 0)
        __hip_atomic_fetch_add(c, 1u, __ATOMIC_RELAXED, __HIP_MEMORY_SCOPE_AGENT);
}

// ---------------- one-time repack: fragment-ordered fp16 images (unchanged) ----------------
__global__ void repack_kernel(const float* __restrict__ x,
                              const float* __restrict__ W0, const float* __restrict__ W1,
                              const float* __restrict__ W2, const float* __restrict__ P0,
                              const float* __restrict__ P1, const float* __restrict__ P2,
                              _Float16* __restrict__ Wfrag, _Float16* __restrict__ Pfrag,
                              _Float16* __restrict__ x16)
{
    size_t idx = (size_t)blockIdx.x * 256 + threadIdx.x;
    if (idx < W_HALFS) {
        int slab = (int)(idx >> 17);          // /131072
        int l = slab / 12, ht = slab % 12;
        int r  = (int)(idx & 131071);
        int kc = r >> 13;                      // /8192
        int r2 = r & 8191;
        int g  = r2 >> 11;
        int cf = (r2 >> 9) & 3;
        int u  = r2 & 511;
        int lane = u >> 3, e = u & 7;
        int qd = lane >> 4, ln = lane & 15;
        int k   = kc * 32 + qd * 8 + e;
        int col = g * Hdim + ht * 64 + cf * 16 + ln;
        float v;
        if (l == 0)      v = (k < 296) ? W0[(size_t)k * 3072 + col] : 0.0f;
        else if (l == 1) v = W1[(size_t)k * 3072 + col];
        else             v = W2[(size_t)k * 3072 + col];
        Wfrag[idx] = (_Float16)v;
    } else if (idx < W_HALFS + P_HALFS) {
        size_t i = idx - W_HALFS;
        int l = (int)(i / 196608);
        int r = (int)(i % 196608);
        int cq = r / 49152;
        int r2 = r % 49152;
        int kc = r2 / 2048;
        int r3 = r2 & 2047;
        int cgr = r3 >> 9;
        int u  = r3 & 511;
        int lane = u >> 3, e = u & 7;
        int qd = lane >> 4, ln = lane & 15;
        int k  = kc * 32 + qd * 8 + e;
        int pj = cq * 64 + cgr * 16 + ln;
        const float* P = (l == 0) ? P0 : (l == 1) ? P1 : P2;
        Pfrag[i] = (_Float16)P[(size_t)k * PJdim + pj];
    } else if (idx < W_HALFS + P_HALFS + X_HALFS) {
        size_t i = idx - W_HALFS - P_HALFS;
        x16[i] = (_Float16)x[i];
    }
}

// ---------------- gate step body: bulk-staged GEMM + 2-pass elementwise ----------------
// block: 128 rows x (4 gates x 64 hcols); 8 waves; wave (g=wv>>1, hh=wv&1) owns
// 128 rows x 32 cols of gate g. Weights resident in Breg.
// Ast holds a full K=256 half-panel (8 kc): 3 barriers per step for the GEMM.
// Elementwise: 2 passes of 64 rows through 64KB zst; thread owns (row, 8 hcols);
// bias from 1KB LDS bst; m stored as one uint4 per pass.
__device__ __forceinline__ void gate_step(
    int l, int b0r, int h0, int KC, int t,
    const half8 (&Breg)[16][2], float (&c)[2][8],
    const _Float16* __restrict__ x16, const _Float16* __restrict__ h16,
    const _Float16* __restrict__ zerop, _Float16* __restrict__ mbuf,
    _Float16* __restrict__ Ast, float* __restrict__ zst, const float* __restrict__ bst,
    int tid)
{
    const int wv = tid >> 6, lane = tid & 63, qd = lane >> 4, ln = lane & 15;
    const int g = wv >> 1, hh = wv & 1;
    const int qd8 = qd * 8;
    const int rowg = b0r + wv * 16 + ln;                    // staging row for this lane

    const _Float16* xt  = x16 + ((size_t)t * Bdim + rowg) * 40;
    const _Float16* h0b = h16 + (size_t)rowg * PJdim - 40;                       // l==0, k in [40,296)
    const _Float16* lob = (l > 0) ? h16 + ((size_t)(l - 1) * Bdim + rowg) * PJdim : nullptr;
    const _Float16* hib = h16 + ((size_t)l * Bdim + rowg) * PJdim - 256;         // l>0, k>=256

    auto srcp = [&](int kc) -> const _Float16* {
        int k = kc * 32 + qd8;
        if (l == 0) return (k < 40) ? xt + k : (k < 296) ? h0b + k : zerop;
        return (k < 256) ? lob + k : hib + k;
    };

    floatx4 acc[8][2];
    const floatx4 fz = {0.f, 0.f, 0.f, 0.f};
#pragma unroll
    for (int i = 0; i < 8; ++i) { acc[i][0] = fz; acc[i][1] = fz; }

    _Float16* Aw = Ast + wv * 512 + lane * 8;

    // ---- half 0: kc 0..7 ----
    uint4 pre[8];
#pragma unroll
    for (int kk = 0; kk < 8; ++kk) pre[kk] = *(const uint4*)srcp(kk);
#pragma unroll
    for (int kk = 0; kk < 8; ++kk) *(uint4*)(Aw + (size_t)kk * 4096) = pre[kk];
    // ---- issue half-1 loads (consumed after the H0-MFMA barrier) ----
    const int n1 = KC - 8;                        // 2 (l==0) or 8
    uint4 pre2[8];
#pragma unroll
    for (int kk = 0; kk < 8; ++kk) if (kk < n1) pre2[kk] = *(const uint4*)srcp(8 + kk);
    __syncthreads();
#pragma unroll
    for (int kk = 0; kk < 8; ++kk) {
        const _Float16* Ab = Ast + (size_t)kk * 4096;
#pragma unroll
        for (int rf = 0; rf < 8; ++rf) {
            half8 af = *(const half8*)(Ab + rf * 512 + lane * 8);
            acc[rf][0] = __builtin_amdgcn_mfma_f32_16x16x32_f16(af, Breg[kk][0], acc[rf][0], 0, 0, 0);
            acc[rf][1] = __builtin_amdgcn_mfma_f32_16x16x32_f16(af, Breg[kk][1], acc[rf][1], 0, 0, 0);
        }
    }
    __syncthreads();                               // H0 reads done -> Ast reusable
    // ---- half 1: kc 8..KC-1 ----
#pragma unroll
    for (int kk = 0; kk < 8; ++kk) if (kk < n1) *(uint4*)(Aw + (size_t)kk * 4096) = pre2[kk];
    __syncthreads();
#pragma unroll
    for (int kk = 0; kk < 8; ++kk) if (kk < n1) {
        const _Float16* Ab = Ast + (size_t)kk * 4096;
#pragma unroll
        for (int rf = 0; rf < 8; ++rf) {
            half8 af = *(const half8*)(Ab + rf * 512 + lane * 8);
            acc[rf][0] = __builtin_amdgcn_mfma_f32_16x16x32_f16(af, Breg[8 + kk][0], acc[rf][0], 0, 0, 0);
            acc[rf][1] = __builtin_amdgcn_mfma_f32_16x16x32_f16(af, Breg[8 + kk][1], acc[rf][1], 0, 0, 0);
        }
    }

    // ---- elementwise: 2 passes of 64 rows through zst ----
    const int trow = tid >> 3;            // 0..63 (row within pass)
    const int hcb  = (tid & 7) * 8;       // 8-col group within 64
#pragma unroll
    for (int p = 0; p < 2; ++p) {
        __syncthreads();                  // prev pass reads done (p=0: MFMA done; zst disjoint from Ast)
#pragma unroll
        for (int rq = 0; rq < 4; ++rq) {  // rf = p*4+rq covers pass rows [rq*16, rq*16+16)
#pragma unroll
            for (int cf = 0; cf < 2; ++cf)
#pragma unroll
                for (int r = 0; r < 4; ++r)
                    zst[(rq * 16 + qd * 4 + r) * 256 + g * 64 + hh * 32 + cf * 16 + ln]
                        = acc[p * 4 + rq][cf][r];
        }
        __syncthreads();
        const float* zrow = zst + trow * 256;
        float zi[8], zj[8], zf[8], zo[8], bi[8], bj[8], bf[8], bo[8];
        *(float4*)(zi)     = *(const float4*)(zrow + hcb);
        *(float4*)(zi + 4) = *(const float4*)(zrow + hcb + 4);
        *(float4*)(zj)     = *(const float4*)(zrow + 64 + hcb);
        *(float4*)(zj + 4) = *(const float4*)(zrow + 64 + hcb + 4);
        *(float4*)(zf)     = *(const float4*)(zrow + 128 + hcb);
        *(float4*)(zf + 4) = *(const float4*)(zrow + 128 + hcb + 4);
        *(float4*)(zo)     = *(const float4*)(zrow + 192 + hcb);
        *(float4*)(zo + 4) = *(const float4*)(zrow + 192 + hcb + 4);
        *(float4*)(bi)     = *(const float4*)(bst + hcb);
        *(float4*)(bi + 4) = *(const float4*)(bst + hcb + 4);
        *(float4*)(bj)     = *(const float4*)(bst + 64 + hcb);
        *(float4*)(bj + 4) = *(const float4*)(bst + 64 + hcb + 4);
        *(float4*)(bf)     = *(const float4*)(bst + 128 + hcb);
        *(float4*)(bf + 4) = *(const float4*)(bst + 128 + hcb + 4);
        *(float4*)(bo)     = *(const float4*)(bst + 192 + hcb);
        *(float4*)(bo + 4) = *(const float4*)(bst + 192 + hcb + 4);
        union { _Float16 h[8]; uint4 v; } pk;
#pragma unroll
        for (int u = 0; u < 8; ++u) {
            float cn = sigm(zf[u] + bf[u]) * c[p][u] + sigm(zi[u] + bi[u]) * tanh_fast(zj[u] + bj[u]);
            c[p][u] = cn;
            pk.h[u] = (_Float16)(sigm(zo[u] + bo[u]) * tanh_fast(cn));
        }
        *(uint4*)(mbuf + ((size_t)l * Bdim + b0r + p * 64 + trow) * Hdim + h0 + hcb) = pk.v;
    }
}

// ---------------- proj step body: 128 rows x 64 pjcols, K=768, 3 bulk stages ----------------
__device__ __forceinline__ void proj_step(
    int l, int b0r, int cq, const half8 (&Preg)[24],
    const _Float16* __restrict__ mbuf, _Float16* __restrict__ h16,
    _Float16* __restrict__ Ast, int tid, bool xstore)
{
    const int wv = tid >> 6, lane = tid & 63, qd = lane >> 4, ln = lane & 15;
    const int rh = wv >> 2, cgi = wv & 3;
    const int rowg = b0r + wv * 16 + ln;
    const _Float16* mrow = mbuf + ((size_t)l * Bdim + rowg) * Hdim + qd * 8;
    _Float16* Aw = Ast + wv * 512 + lane * 8;

    floatx4 pacc[4];
    const floatx4 fz = {0.f, 0.f, 0.f, 0.f};
#pragma unroll
    for (int i = 0; i < 4; ++i) pacc[i] = fz;

    uint4 pa[8], pb[8];
#pragma unroll
    for (int kk = 0; kk < 8; ++kk) pa[kk] = *(const uint4*)(mrow + kk * 32);
#pragma unroll
    for (int kk = 0; kk < 8; ++kk) *(uint4*)(Aw + (size_t)kk * 4096) = pa[kk];
#pragma unroll
    for (int kk = 0; kk < 8; ++kk) pa[kk] = *(const uint4*)(mrow + (8 + kk) * 32);
    __syncthreads();
#pragma unroll
    for (int kk = 0; kk < 8; ++kk) {
        const _Float16* Ab = Ast + (size_t)kk * 4096;
#pragma unroll
        for (int rfl = 0; rfl < 4; ++rfl) {
            half8 af = *(const half8*)(Ab + (rh * 4 + rfl) * 512 + lane * 8);
            pacc[rfl] = __builtin_amdgcn_mfma_f32_16x16x32_f16(af, Preg[kk], pacc[rfl], 0, 0, 0);
        }
    }
    __syncthreads();
#pragma unroll
    for (int kk = 0; kk < 8; ++kk) *(uint4*)(Aw + (size_t)kk * 4096) = pa[kk];
#pragma unroll
    for (int kk = 0; kk < 8; ++kk) pb[kk] = *(const uint4*)(mrow + (16 + kk) * 32);
    __syncthreads();
#pragma unroll
    for (int kk = 0; kk < 8; ++kk) {
        const _Float16* Ab = Ast + (size_t)kk * 4096;
#pragma unroll
        for (int rfl = 0; rfl < 4; ++rfl) {
            half8 af = *(const half8*)(Ab + (rh * 4 + rfl) * 512 + lane * 8);
            pacc[rfl] = __builtin_amdgcn_mfma_f32_16x16x32_f16(af, Preg[8 + kk], pacc[rfl], 0, 0, 0);
        }
    }
    __syncthreads();
#pragma unroll
    for (int kk = 0; kk < 8; ++kk) *(uint4*)(Aw + (size_t)kk * 4096) = pb[kk];
    __syncthreads();
#pragma unroll
    for (int kk = 0; kk < 8; ++kk) {
        const _Float16* Ab = Ast + (size_t)kk * 4096;
#pragma unroll
        for (int rfl = 0; rfl < 4; ++rfl) {
            half8 af = *(const half8*)(Ab + (rh * 4 + rfl) * 512 + lane * 8);
            pacc[rfl] = __builtin_amdgcn_mfma_f32_16x16x32_f16(af, Preg[16 + kk], pacc[rfl], 0, 0, 0);
        }
    }

    if (xstore) {
#pragma unroll
        for (int rfl = 0; rfl < 4; ++rfl)
#pragma unroll
            for (int r = 0; r < 4; ++r) {
                int row = b0r + (rh * 4 + rfl) * 16 + qd * 4 + r;
                st_coh16b(h16 + ((size_t)l * Bdim + row) * PJdim + cq * 64 + cgi * 16 + ln,
                          (_Float16)pacc[rfl][r]);
            }
    } else {
#pragma unroll
        for (int rfl = 0; rfl < 4; ++rfl)
#pragma unroll
            for (int r = 0; r < 4; ++r) {
                int row = b0r + (rh * 4 + rfl) * 16 + qd * 4 + r;
                h16[((size_t)l * Bdim + row) * PJdim + cq * 64 + cgi * 16 + ln] = (_Float16)pacc[rfl][r];
            }
    }
}

__device__ __forceinline__ void load_Breg(const _Float16* __restrict__ Wfrag, int l, int ht,
                                          int wv, int lane, half8 (&Breg)[16][2])
{
    const int g = wv >> 1, hh = wv & 1;
    const _Float16* wslab = Wfrag + ((size_t)(l * 12 + ht)) * 131072;
#pragma unroll
    for (int kc = 0; kc < 16; ++kc)
#pragma unroll
        for (int cf = 0; cf < 2; ++cf)
            Breg[kc][cf] = *(const half8*)(wslab + kc * 8192 + g * 2048 + (hh * 2 + cf) * 512 + lane * 8);
}

__device__ __forceinline__ void load_Preg(const _Float16* __restrict__ Pfrag, int l, int cq,
                                          int wv, int lane, half8 (&Preg)[24])
{
    const int cgi = wv & 3;
    const _Float16* pslab = Pfrag + (size_t)l * 196608 + (size_t)cq * 49152;
#pragma unroll
    for (int kc = 0; kc < 24; ++kc)
        Preg[kc] = *(const half8*)(pslab + kc * 2048 + cgi * 512 + lane * 8);
}

__device__ __forceinline__ void load_bst(const float* __restrict__ bias, int h0, int tid,
                                         float* __restrict__ bst)
{
    if (tid < 256) {
        int gg = tid >> 6, u = tid & 63;
        bst[tid] = bias[gg * Hdim + h0 + u] + ((gg == 2) ? 1.0f : 0.0f);  // forget bias folded
    }
}

__device__ __forceinline__ void finalize_row(const _Float16* __restrict__ h16,
                                             float* __restrict__ out, int row, int lane)
{
    const _Float16* e = h16 + ((size_t)2 * Bdim + row) * PJdim + lane * 4;
    float v0 = (float)e[0], v1 = (float)e[1], v2 = (float)e[2], v3 = (float)e[3];
    float ss = v0 * v0 + v1 * v1 + v2 * v2 + v3 * v3;
#pragma unroll
    for (int o = 32; o > 0; o >>= 1) ss += __shfl_xor(ss, o, 64);
    float rs = rsqrtf(fmaxf(ss, 1e-12f));
    float4 o4; o4.x = v0 * rs; o4.y = v1 * rs; o4.z = v2 * rs; o4.w = v3 * rs;
    *(float4*)(out + (size_t)row * PJdim + lane * 4) = o4;
}

// ---------------- persistent kernel ----------------
// LDS = Ast 64KB + zst 64KB + bst 1KB = 129KB  ->  occupancy 1 block/CU BY
// CONSTRUCTION: no two pipeline blocks can share a CU, eliminating the
// co-residency straggler coupling (the leading theory for the 2.5x gap
// between the ~11us/step model and the ~30us/step measurement).
// Hazard/DAG audit identical to R3 (see comments there).
__global__ __launch_bounds__(512)
void lstm_persist(const _Float16* __restrict__ x16, const _Float16* __restrict__ Wfrag,
                  const _Float16* __restrict__ Pfrag,
                  const float* __restrict__ bias0, const float* __restrict__ bias1,
                  const float* __restrict__ bias2,
                  _Float16* __restrict__ h16, _Float16* __restrict__ mbuf,
                  const _Float16* __restrict__ zerop, float* __restrict__ out,
                  unsigned* __restrict__ flags)
{
    __shared__ __align__(16) _Float16 Ast[8 * 4096];   // 64 KiB: one K=256 half-panel
    __shared__ __align__(16) float zst[64 * 256];      // 64 KiB: 64-row elementwise pass
    __shared__ __align__(16) float bst[256];           // 1 KiB: 4 gates x 64 bias

    const int tid = threadIdx.x, bid = blockIdx.x;
    const int wv = tid >> 6, lane = tid & 63;

    // XCD-grouped role mapping: gid lives on XCD gid>>1 (assuming bid%8=XCD)
    const int xcd = bid & 7, slot = bid >> 3;
    const int gid = xcd * 2 + (slot >> 4);
    const int rr  = slot & 15;
    if (gid >= 15) return;                              // 16 idle blocks exit
    const int bt2 = gid / 3, l = gid % 3;
    const int b0r = bt2 * 128;

    unsigned* gd = flags + (size_t)gid * 64;            // 256B-spread counters
    unsigned* pd = gd + 32;

    if (rr < 12) {                                      // ---- gate block ----
        const int ht = rr, h0 = ht * 64;
        const int KC = (l == 0) ? 10 : 16;
        half8 Breg[16][2];
        load_Breg(Wfrag, l, ht, wv, lane, Breg);
        load_bst((l == 0) ? bias0 : (l == 1) ? bias1 : bias2, h0, tid, bst);
        float c[2][8];
#pragma unroll
        for (int p = 0; p < 2; ++p)
#pragma unroll
            for (int u = 0; u < 8; ++u) c[p][u] = 0.f;
        unsigned* pd_lo = (l > 0) ? flags + (size_t)(gid - 1) * 64 + 32 : nullptr;
        for (int t = 0; t < Tdim; ++t) {
            pipe_wait(pd, 4u * (unsigned)t, pd_lo, (l > 0) ? 4u * (unsigned)(t + 1) : 0u);
            gate_step(l, b0r, h0, KC, t, Breg, c,
                      x16, h16, zerop, mbuf, Ast, zst, bst, tid);
            pipe_sig(gd);
        }
        if (l == 2 && rr < 8) {                         // finalize: 8 blocks x 16 rows per gid
            pipe_wait(pd, 4u * (unsigned)Tdim, nullptr, 0u);
            int row0 = b0r + rr * 16 + wv * 2;
            finalize_row(h16, out, row0, lane);
            finalize_row(h16, out, row0 + 1, lane);
        }
    } else {                                            // ---- proj block ----
        const int cq = rr - 12;
        const bool xstore = ((gid & 1) == 1) && (gid + 1 < 15) && ((gid + 1) % 3 != 0);
        half8 Preg[24];
        load_Preg(Pfrag, l, cq, wv, lane, Preg);
        unsigned* gd_hi = (l < 2) ? flags + (size_t)(gid + 1) * 64 : nullptr;
        for (int t = 0; t < Tdim; ++t) {
            pipe_wait(gd, 12u * (unsigned)(t + 1), gd_hi, (l < 2) ? 12u * (unsigned)t : 0u);
            proj_step(l, b0r, cq, Preg, mbuf, h16, Ast, tid, xstore);
            pipe_sig(pd);
        }
    }
}

// ---------------- fallback: per-step kernels, c-state in global ----------------
__global__ __launch_bounds__(512)
void gate_fb(const _Float16* __restrict__ x16, const _Float16* __restrict__ Wfrag,
             const float* __restrict__ bias0, const float* __restrict__ bias1,
             const float* __restrict__ bias2,
             _Float16* __restrict__ h16, _Float16* __restrict__ mbuf,
             const _Float16* __restrict__ zerop, float* __restrict__ cfb, int s)
{
    __shared__ __align__(16) _Float16 Ast[8 * 4096];
    __shared__ __align__(16) float zst[64 * 256];
    __shared__ __align__(16) float bst[256];
    const int tid = threadIdx.x, bid = blockIdx.x;
    const int ht = bid % 12, z = bid / 12, l = z % 3, bt2 = z / 3;
    const int t = s - l;
    if (t < 0 || t >= Tdim) return;
    const int wv = tid >> 6, lane = tid & 63;
    const int b0r = bt2 * 128, h0 = ht * 64;
    const int KC = (l == 0) ? 10 : 16;
    half8 Breg[16][2];
    load_Breg(Wfrag, l, ht, wv, lane, Breg);
    load_bst((l == 0) ? bias0 : (l == 1) ? bias1 : bias2, h0, tid, bst);
    const int trow = tid >> 3, hcb = (tid & 7) * 8;
    float c[2][8];
#pragma unroll
    for (int p = 0; p < 2; ++p)
#pragma unroll
        for (int u = 0; u < 8; ++u)
            c[p][u] = cfb[((size_t)l * Bdim + b0r + p * 64 + trow) * Hdim + h0 + hcb + u];
    gate_step(l, b0r, h0, KC, t, Breg, c, x16, h16, zerop, mbuf, Ast, zst, bst, tid);
#pragma unroll
    for (int p = 0; p < 2; ++p)
#pragma unroll
        for (int u = 0; u < 8; ++u)
            cfb[((size_t)l * Bdim + b0r + p * 64 + trow) * Hdim + h0 + hcb + u] = c[p][u];
}

__global__ __launch_bounds__(512)
void proj_fb(const _Float16* __restrict__ Pfrag, const _Float16* __restrict__ mbuf,
             _Float16* __restrict__ h16, int s)
{
    __shared__ __align__(16) _Float16 Ast[8 * 4096];
    const int tid = threadIdx.x, bid = blockIdx.x;
    const int cq = bid & 3, z = bid >> 2, l = z % 3, bt2 = z / 3;
    const int tp = s - l;
    if (tp < 0 || tp >= Tdim) return;
    const int wv = tid >> 6, lane = tid & 63;
    half8 Preg[24];
    load_Preg(Pfrag, l, cq, wv, lane, Preg);
    proj_step(l, bt2 * 128, cq, Preg, mbuf, h16, Ast, tid, false);
}

__global__ __launch_bounds__(512)
void fin_fb(const _Float16* __restrict__ h16, float* __restrict__ out)
{
    int row = blockIdx.x * 8 + (threadIdx.x >> 6);
    finalize_row(h16, out, row, threadIdx.x & 63);
}

extern "C" void kernel_launch(void* const* d_in, const int* in_sizes, int n_in,
                              void* d_out, int out_size, void* d_ws, size_t ws_size,
                              hipStream_t stream)
{
    (void)in_sizes; (void)n_in; (void)out_size; (void)ws_size;
    const float* x  = (const float*)d_in[0];
    const float* W0 = (const float*)d_in[1];
    const float* b0 = (const float*)d_in[2];
    const float* P0 = (const float*)d_in[3];
    const float* W1 = (const float*)d_in[4];
    const float* b1 = (const float*)d_in[5];
    const float* P1 = (const float*)d_in[6];
    const float* W2 = (const float*)d_in[7];
    const float* b2 = (const float*)d_in[8];
    const float* P2 = (const float*)d_in[9];

    char* ws = (char*)d_ws;
    _Float16* h16   = (_Float16*)(ws);
    _Float16* zerop = (_Float16*)(ws + ZP_OFF);
    _Float16* mbuf  = (_Float16*)(ws + MB_OFF);
    _Float16* x16   = (_Float16*)(ws + X_OFF);
    _Float16* Wfrag = (_Float16*)(ws + W_OFF);
    _Float16* Pfrag = (_Float16*)(ws + P_OFF);
    float*    cfb   = (float*)(ws + C_OFF);
    unsigned* flags = (unsigned*)(ws + C_OFF);   // coop path only; aliases cfb (fallback-only)
    float*    outp  = (float*)d_out;

    // zero h state + zero page (+ fallback c / pipe flags — same region)
    hipMemsetAsync(ws, 0, ZP_OFF + 256, stream);
    hipMemsetAsync(cfb, 0, C_BYTES, stream);

    {
        constexpr size_t total = W_HALFS + P_HALFS + X_HALFS;
        int grid = (int)((total + 255) / 256);
        repack_kernel<<<grid, 256, 0, stream>>>(x, W0, W1, W2, P0, P1, P2, Wfrag, Pfrag, x16);
    }

    int occ = 0;
    hipError_t oe = hipOccupancyMaxActiveBlocksPerMultiprocessor(&occ, lstm_persist, 512, 0);
    bool coop = (oe == hipSuccess && occ >= 1);
    if (coop) {
        void* args[] = { (void*)&x16, (void*)&Wfrag, (void*)&Pfrag,
                         (void*)&b0, (void*)&b1, (void*)&b2,
                         (void*)&h16, (void*)&mbuf, (void*)&zerop, (void*)&outp,
                         (void*)&flags };
        hipError_t le = hipLaunchCooperativeKernel((const void*)lstm_persist,
                                                   dim3(256), dim3(512), args, 0, stream);
        if (le != hipSuccess) { (void)hipGetLastError(); coop = false; }
    }
    if (!coop) {
        for (int s = 0; s < NSTEP; ++s) {
            gate_fb<<<180, 512, 0, stream>>>(x16, Wfrag, b0, b1, b2, h16, mbuf, zerop, cfb, s);
            proj_fb<<<60, 512, 0, stream>>>(Pfrag, mbuf, h16, s);
        }
        fin_fb<<<80, 512, 0, stream>>>(h16, outp);
    }
}

// Round 5
// 5148.311 us; speedup vs baseline: 1.4456x; 1.4456x over previous
//
#include <hip/hip_runtime.h>

#define Bdim 640
#define Hdim 768
#define PJdim 256
#define Tdim 160
#define NSTEP (Tdim + 2)

typedef _Float16 half8 __attribute__((ext_vector_type(8)));
typedef float floatx4 __attribute__((ext_vector_type(4)));

// ---------------- workspace layout (halfs/bytes) ----------------
constexpr size_t HB_HALFS = 3ull * Bdim * PJdim;            // 491,520
constexpr size_t ZP_OFF   = HB_HALFS * 2;                   // byte offset
constexpr size_t MB_OFF   = ZP_OFF + 256;
constexpr size_t MB_HALFS = 3ull * Bdim * Hdim;             // 1,474,560
constexpr size_t X_OFF    = MB_OFF + MB_HALFS * 2;
constexpr size_t X_HALFS  = (size_t)Tdim * Bdim * 40;       // 4,096,000
constexpr size_t W_OFF    = X_OFF + X_HALFS * 2;
constexpr size_t W_HALFS  = 36ull * 131072;                 // 4,718,592
constexpr size_t P_OFF    = W_OFF + W_HALFS * 2;
constexpr size_t P_HALFS  = 3ull * 196608;                  // 589,824
constexpr size_t C_OFF    = P_OFF + P_HALFS * 2;
constexpr size_t C_BYTES  = 3ull * Bdim * Hdim * 4;

__device__ __forceinline__ float sigm(float v) { return 1.0f / (1.0f + __expf(-v)); }
__device__ __forceinline__ float tanh_fast(float v) { return 2.0f / (1.0f + __expf(-2.0f * v)) - 1.0f; }

// Async global->LDS, 16B per lane. HW: per-lane GLOBAL src address; LDS dst =
// wave-uniform base + lane*16. Our fragment layout is exactly that contract.
// Costs ZERO VGPRs (fixes R4's scratch-spill catastrophe: 6.4GB HBM from
// pre[8]/pre2[8] staging arrays).
__device__ __forceinline__ void stage16(void* lds, const void* g)
{
    __builtin_amdgcn_global_load_lds(
        (const __attribute__((address_space(1))) void*)g,
        (__attribute__((address_space(3))) void*)lds,
        16, 0, 0);
}
__device__ __forceinline__ void wait_vm0() {
    asm volatile("s_waitcnt vmcnt(0)" ::: "memory");
}

// Device-coherent 2B store (bypass L1/L2, lands at coherence point).
// Used ONLY by cross-XCD h16 producer edges.
__device__ __forceinline__ void st_coh16b(void* p, _Float16 h) {
    union { _Float16 h; unsigned short u; } cv; cv.h = h;
    __hip_atomic_store((unsigned short*)p, cv.u, __ATOMIC_RELAXED, __HIP_MEMORY_SCOPE_AGENT);
}

// ---------------- fine-grained pipeline sync (R3 semantics, validated) ----------------
__device__ __forceinline__ void pipe_wait(unsigned* c0, unsigned t0, unsigned* c1, unsigned t1)
{
    if (threadIdx.x == 0) {
        if (t0)
            while (__hip_atomic_load(c0, __ATOMIC_RELAXED, __HIP_MEMORY_SCOPE_AGENT) < t0)
                __builtin_amdgcn_s_sleep(1);
        if (c1 && t1)
            while (__hip_atomic_load(c1, __ATOMIC_RELAXED, __HIP_MEMORY_SCOPE_AGENT) < t1)
                __builtin_amdgcn_s_sleep(1);
        __builtin_amdgcn_fence(__ATOMIC_ACQUIRE, "agent");   // inv only, no wbl2
    }
    __syncthreads();
}

__device__ __forceinline__ void pipe_sig(unsigned* c)
{
    __syncthreads();                // drains vmcnt: stores visible at shared L2 / LLC
    if (threadIdx.x == 0)
        __hip_atomic_fetch_add(c, 1u, __ATOMIC_RELAXED, __HIP_MEMORY_SCOPE_AGENT);
}

// ---------------- one-time repack: fragment-ordered fp16 images (unchanged) ----------------
__global__ void repack_kernel(const float* __restrict__ x,
                              const float* __restrict__ W0, const float* __restrict__ W1,
                              const float* __restrict__ W2, const float* __restrict__ P0,
                              const float* __restrict__ P1, const float* __restrict__ P2,
                              _Float16* __restrict__ Wfrag, _Float16* __restrict__ Pfrag,
                              _Float16* __restrict__ x16)
{
    size_t idx = (size_t)blockIdx.x * 256 + threadIdx.x;
    if (idx < W_HALFS) {
        int slab = (int)(idx >> 17);          // /131072
        int l = slab / 12, ht = slab % 12;
        int r  = (int)(idx & 131071);
        int kc = r >> 13;                      // /8192
        int r2 = r & 8191;
        int g  = r2 >> 11;
        int cf = (r2 >> 9) & 3;
        int u  = r2 & 511;
        int lane = u >> 3, e = u & 7;
        int qd = lane >> 4, ln = lane & 15;
        int k   = kc * 32 + qd * 8 + e;
        int col = g * Hdim + ht * 64 + cf * 16 + ln;
        float v;
        if (l == 0)      v = (k < 296) ? W0[(size_t)k * 3072 + col] : 0.0f;
        else if (l == 1) v = W1[(size_t)k * 3072 + col];
        else             v = W2[(size_t)k * 3072 + col];
        Wfrag[idx] = (_Float16)v;
    } else if (idx < W_HALFS + P_HALFS) {
        size_t i = idx - W_HALFS;
        int l = (int)(i / 196608);
        int r = (int)(i % 196608);
        int cq = r / 49152;
        int r2 = r % 49152;
        int kc = r2 / 2048;
        int r3 = r2 & 2047;
        int cgr = r3 >> 9;
        int u  = r3 & 511;
        int lane = u >> 3, e = u & 7;
        int qd = lane >> 4, ln = lane & 15;
        int k  = kc * 32 + qd * 8 + e;
        int pj = cq * 64 + cgr * 16 + ln;
        const float* P = (l == 0) ? P0 : (l == 1) ? P1 : P2;
        Pfrag[i] = (_Float16)P[(size_t)k * PJdim + pj];
    } else if (idx < W_HALFS + P_HALFS + X_HALFS) {
        size_t i = idx - W_HALFS - P_HALFS;
        x16[i] = (_Float16)x[i];
    }
}

// ---------------- gate step: async full-panel stage, 5 barriers total ----------------
// block: 128 rows x (4 gates x 64 hcols); 8 waves; wave (g=wv>>1, hh=wv&1) owns
// 128 rows x 32 cols of gate g. Weights resident in Breg.
// Ast holds the ENTIRE K-panel (KC kc-slices, 8KB each); one stage barrier,
// then a barrier-free 16-kc MFMA loop; zst aliases Ast (GEMM done by then).
__device__ __forceinline__ void gate_step(
    int l, int b0r, int h0, int KC, int t,
    const half8 (&Breg)[16][2], float (&c)[2][8],
    const _Float16* __restrict__ x16, const _Float16* __restrict__ h16,
    const _Float16* __restrict__ zerop, _Float16* __restrict__ mbuf,
    _Float16* __restrict__ Ast, float* __restrict__ zstA, float* __restrict__ zstB,
    const float* __restrict__ bst, int tid)
{
    const int wv = tid >> 6, lane = tid & 63, qd = lane >> 4, ln = lane & 15;
    const int g = wv >> 1, hh = wv & 1;
    const int qd8 = qd * 8;
    const int rowg = b0r + wv * 16 + ln;                    // staging row for this lane

    const _Float16* xt  = x16 + ((size_t)t * Bdim + rowg) * 40;
    const _Float16* h0b = h16 + (size_t)rowg * PJdim - 40;                       // l==0, k in [40,296)
    const _Float16* lob = (l > 0) ? h16 + ((size_t)(l - 1) * Bdim + rowg) * PJdim : nullptr;
    const _Float16* hib = h16 + ((size_t)l * Bdim + rowg) * PJdim - 256;         // l>0, k>=256

    auto srcp = [&](int kc) -> const _Float16* {
        int k = kc * 32 + qd8;
        if (l == 0) return (k < 40) ? xt + k : (k < 296) ? h0b + k : zerop;
        return (k < 256) ? lob + k : hib + k;
    };

    // ---- async stage the whole panel (no VGPR staging, no per-chunk barriers)
    _Float16* wbase = Ast + wv * 512;                      // +kc*4096 halfs per slice
#pragma unroll
    for (int kc = 0; kc < 16; ++kc)
        if (kc < KC) stage16(wbase + (size_t)kc * 4096, srcp(kc));
    wait_vm0();
    __syncthreads();                                       // panel ready

    floatx4 acc[8][2];
    const floatx4 fz = {0.f, 0.f, 0.f, 0.f};
#pragma unroll
    for (int i = 0; i < 8; ++i) { acc[i][0] = fz; acc[i][1] = fz; }

#pragma unroll
    for (int kc = 0; kc < 16; ++kc)
        if (kc < KC) {
            const _Float16* Ab = Ast + (size_t)kc * 4096;
#pragma unroll
            for (int rf = 0; rf < 8; ++rf) {
                half8 af = *(const half8*)(Ab + rf * 512 + lane * 8);
                acc[rf][0] = __builtin_amdgcn_mfma_f32_16x16x32_f16(af, Breg[kc][0], acc[rf][0], 0, 0, 0);
                acc[rf][1] = __builtin_amdgcn_mfma_f32_16x16x32_f16(af, Breg[kc][1], acc[rf][1], 0, 0, 0);
            }
        }
    __syncthreads();                                       // Ast reads done; zst aliases Ast

    // ---- scatter z into both 64-row pass regions (disjoint -> no barrier between)
#pragma unroll
    for (int p = 0; p < 2; ++p) {
        float* zp = p ? zstB : zstA;
#pragma unroll
        for (int rq = 0; rq < 4; ++rq)
#pragma unroll
            for (int cf = 0; cf < 2; ++cf)
#pragma unroll
                for (int r = 0; r < 4; ++r)
                    zp[(rq * 16 + qd * 4 + r) * 256 + g * 64 + hh * 32 + cf * 16 + ln]
                        = acc[p * 4 + rq][cf][r];
    }
    __syncthreads();

    // ---- elementwise: thread owns (row trow, 8 hcols) per pass
    const int trow = tid >> 3, hcb = (tid & 7) * 8;
#pragma unroll
    for (int p = 0; p < 2; ++p) {
        const float* zrow = (p ? zstB : zstA) + trow * 256;
        union { _Float16 h[8]; uint4 v; } pk;
#pragma unroll
        for (int q = 0; q < 2; ++q) {
            const int o = q * 4;
            float4 zi = *(const float4*)(zrow + hcb + o);
            float4 zj = *(const float4*)(zrow + 64 + hcb + o);
            float4 zf = *(const float4*)(zrow + 128 + hcb + o);
            float4 zo = *(const float4*)(zrow + 192 + hcb + o);
            float4 bi = *(const float4*)(bst + hcb + o);
            float4 bj = *(const float4*)(bst + 64 + hcb + o);
            float4 bf = *(const float4*)(bst + 128 + hcb + o);
            float4 bo = *(const float4*)(bst + 192 + hcb + o);
            float cn0 = sigm(zf.x + bf.x) * c[p][o + 0] + sigm(zi.x + bi.x) * tanh_fast(zj.x + bj.x);
            float cn1 = sigm(zf.y + bf.y) * c[p][o + 1] + sigm(zi.y + bi.y) * tanh_fast(zj.y + bj.y);
            float cn2 = sigm(zf.z + bf.z) * c[p][o + 2] + sigm(zi.z + bi.z) * tanh_fast(zj.z + bj.z);
            float cn3 = sigm(zf.w + bf.w) * c[p][o + 3] + sigm(zi.w + bi.w) * tanh_fast(zj.w + bj.w);
            c[p][o + 0] = cn0; c[p][o + 1] = cn1; c[p][o + 2] = cn2; c[p][o + 3] = cn3;
            pk.h[o + 0] = (_Float16)(sigm(zo.x + bo.x) * tanh_fast(cn0));
            pk.h[o + 1] = (_Float16)(sigm(zo.y + bo.y) * tanh_fast(cn1));
            pk.h[o + 2] = (_Float16)(sigm(zo.z + bo.z) * tanh_fast(cn2));
            pk.h[o + 3] = (_Float16)(sigm(zo.w + bo.w) * tanh_fast(cn3));
        }
        *(uint4*)(mbuf + ((size_t)l * Bdim + b0r + p * 64 + trow) * Hdim + h0 + hcb) = pk.v;
    }
}

// ---------------- proj step: 3 async-staged thirds (K=256 each), 5 barriers ----------------
__device__ __forceinline__ void proj_step(
    int l, int b0r, int cq, const half8 (&Preg)[24],
    const _Float16* __restrict__ mbuf, _Float16* __restrict__ h16,
    _Float16* __restrict__ AstA, _Float16* __restrict__ AstB, int tid, bool xstore)
{
    const int wv = tid >> 6, lane = tid & 63, qd = lane >> 4, ln = lane & 15;
    const int rh = wv >> 2, cgi = wv & 3;
    const int rowg = b0r + wv * 16 + ln;
    const _Float16* mrow = mbuf + ((size_t)l * Bdim + rowg) * Hdim + qd * 8;
    _Float16* wA = AstA + wv * 512;
    _Float16* wB = AstB + wv * 512;

    floatx4 pacc[4];
    const floatx4 fz = {0.f, 0.f, 0.f, 0.f};
#pragma unroll
    for (int i = 0; i < 4; ++i) pacc[i] = fz;

    auto mm = [&](const _Float16* region, int base) {
#pragma unroll
        for (int kk = 0; kk < 8; ++kk) {
            const _Float16* Ab = region + (size_t)kk * 4096;
#pragma unroll
            for (int rfl = 0; rfl < 4; ++rfl) {
                half8 af = *(const half8*)(Ab + (rh * 4 + rfl) * 512 + lane * 8);
                pacc[rfl] = __builtin_amdgcn_mfma_f32_16x16x32_f16(af, Preg[base + kk], pacc[rfl], 0, 0, 0);
            }
        }
    };

#pragma unroll
    for (int kk = 0; kk < 8; ++kk) stage16(wA + (size_t)kk * 4096, mrow + kk * 32);
    wait_vm0();
    __syncthreads();                 // T0 ready
#pragma unroll
    for (int kk = 0; kk < 8; ++kk) stage16(wB + (size_t)kk * 4096, mrow + (8 + kk) * 32);
    mm(AstA, 0);                     // MFMA T0 while T1 lands async
    wait_vm0();
    __syncthreads();                 // T1 ready; all waves done reading A
#pragma unroll
    for (int kk = 0; kk < 8; ++kk) stage16(wA + (size_t)kk * 4096, mrow + (16 + kk) * 32);
    mm(AstB, 8);                     // MFMA T1 while T2 lands
    wait_vm0();
    __syncthreads();                 // T2 ready; all waves done reading B
    mm(AstA, 16);

    if (xstore) {
#pragma unroll
        for (int rfl = 0; rfl < 4; ++rfl)
#pragma unroll
            for (int r = 0; r < 4; ++r) {
                int row = b0r + (rh * 4 + rfl) * 16 + qd * 4 + r;
                st_coh16b(h16 + ((size_t)l * Bdim + row) * PJdim + cq * 64 + cgi * 16 + ln,
                          (_Float16)pacc[rfl][r]);
            }
    } else {
#pragma unroll
        for (int rfl = 0; rfl < 4; ++rfl)
#pragma unroll
            for (int r = 0; r < 4; ++r) {
                int row = b0r + (rh * 4 + rfl) * 16 + qd * 4 + r;
                h16[((size_t)l * Bdim + row) * PJdim + cq * 64 + cgi * 16 + ln] = (_Float16)pacc[rfl][r];
            }
    }
}

__device__ __forceinline__ void load_Breg(const _Float16* __restrict__ Wfrag, int l, int ht,
                                          int wv, int lane, half8 (&Breg)[16][2])
{
    const int g = wv >> 1, hh = wv & 1;
    const _Float16* wslab = Wfrag + ((size_t)(l * 12 + ht)) * 131072;
#pragma unroll
    for (int kc = 0; kc < 16; ++kc)
#pragma unroll
        for (int cf = 0; cf < 2; ++cf)
            Breg[kc][cf] = *(const half8*)(wslab + kc * 8192 + g * 2048 + (hh * 2 + cf) * 512 + lane * 8);
}

__device__ __forceinline__ void load_Preg(const _Float16* __restrict__ Pfrag, int l, int cq,
                                          int wv, int lane, half8 (&Preg)[24])
{
    const int cgi = wv & 3;
    const _Float16* pslab = Pfrag + (size_t)l * 196608 + (size_t)cq * 49152;
#pragma unroll
    for (int kc = 0; kc < 24; ++kc)
        Preg[kc] = *(const half8*)(pslab + kc * 2048 + cgi * 512 + lane * 8);
}

__device__ __forceinline__ void load_bst(const float* __restrict__ bias, int h0, int tid,
                                         float* __restrict__ bst)
{
    if (tid < 256) {
        int gg = tid >> 6, u = tid & 63;
        bst[tid] = bias[gg * Hdim + h0 + u] + ((gg == 2) ? 1.0f : 0.0f);  // forget bias folded
    }
}

__device__ __forceinline__ void finalize_row(const _Float16* __restrict__ h16,
                                             float* __restrict__ out, int row, int lane)
{
    const _Float16* e = h16 + ((size_t)2 * Bdim + row) * PJdim + lane * 4;
    float v0 = (float)e[0], v1 = (float)e[1], v2 = (float)e[2], v3 = (float)e[3];
    float ss = v0 * v0 + v1 * v1 + v2 * v2 + v3 * v3;
#pragma unroll
    for (int o = 32; o > 0; o >>= 1) ss += __shfl_xor(ss, o, 64);
    float rs = rsqrtf(fmaxf(ss, 1e-12f));
    float4 o4; o4.x = v0 * rs; o4.y = v1 * rs; o4.z = v2 * rs; o4.w = v3 * rs;
    *(float4*)(out + (size_t)row * PJdim + lane * 4) = o4;
}

// ---------------- persistent kernel: flag-pipelined, 5 barriers/step/role ----------------
// Hazard/DAG audit identical to R3. LDS map (129KB, single block/CU):
//   gate: Ast [0,128K) staged panel; zstA [0,64K) + zstB [64K,128K) alias Ast
//         (safe: zst written only after the post-GEMM barrier); bst [128K,+1K)
//   proj: AstA [0,64K), AstB [64K,128K) double-buffered K-thirds
__global__ __launch_bounds__(512)
void lstm_persist(const _Float16* __restrict__ x16, const _Float16* __restrict__ Wfrag,
                  const _Float16* __restrict__ Pfrag,
                  const float* __restrict__ bias0, const float* __restrict__ bias1,
                  const float* __restrict__ bias2,
                  _Float16* __restrict__ h16, _Float16* __restrict__ mbuf,
                  const _Float16* __restrict__ zerop, float* __restrict__ out,
                  unsigned* __restrict__ flags)
{
    __shared__ __align__(16) char LDSRAW[132096];
    _Float16* Ast  = (_Float16*)LDSRAW;
    float*    zstA = (float*)LDSRAW;
    float*    zstB = (float*)(LDSRAW + 65536);
    float*    bst  = (float*)(LDSRAW + 131072);

    const int tid = threadIdx.x, bid = blockIdx.x;
    const int wv = tid >> 6, lane = tid & 63;

    // XCD-grouped role mapping: gid lives on XCD gid>>1 (assuming bid%8=XCD)
    const int xcd = bid & 7, slot = bid >> 3;
    const int gid = xcd * 2 + (slot >> 4);
    const int rr  = slot & 15;
    if (gid >= 15) return;                              // 16 idle blocks exit
    const int bt2 = gid / 3, l = gid % 3;
    const int b0r = bt2 * 128;

    unsigned* gd = flags + (size_t)gid * 64;            // 256B-spread counters
    unsigned* pd = gd + 32;

    if (rr < 12) {                                      // ---- gate block ----
        const int ht = rr, h0 = ht * 64;
        const int KC = (l == 0) ? 10 : 16;
        half8 Breg[16][2];
        load_Breg(Wfrag, l, ht, wv, lane, Breg);
        load_bst((l == 0) ? bias0 : (l == 1) ? bias1 : bias2, h0, tid, bst);
        float c[2][8];
#pragma unroll
        for (int p = 0; p < 2; ++p)
#pragma unroll
            for (int u = 0; u < 8; ++u) c[p][u] = 0.f;
        unsigned* pd_lo = (l > 0) ? flags + (size_t)(gid - 1) * 64 + 32 : nullptr;
        for (int t = 0; t < Tdim; ++t) {
            pipe_wait(pd, 4u * (unsigned)t, pd_lo, (l > 0) ? 4u * (unsigned)(t + 1) : 0u);
            gate_step(l, b0r, h0, KC, t, Breg, c,
                      x16, h16, zerop, mbuf, Ast, zstA, zstB, bst, tid);
            pipe_sig(gd);
        }
        if (l == 2 && rr < 8) {                         // finalize: 8 blocks x 16 rows per gid
            pipe_wait(pd, 4u * (unsigned)Tdim, nullptr, 0u);
            int row0 = b0r + rr * 16 + wv * 2;
            finalize_row(h16, out, row0, lane);
            finalize_row(h16, out, row0 + 1, lane);
        }
    } else {                                            // ---- proj block ----
        const int cq = rr - 12;
        const bool xstore = ((gid & 1) == 1) && (gid + 1 < 15) && ((gid + 1) % 3 != 0);
        half8 Preg[24];
        load_Preg(Pfrag, l, cq, wv, lane, Preg);
        unsigned* gd_hi = (l < 2) ? flags + (size_t)(gid + 1) * 64 : nullptr;
        for (int t = 0; t < Tdim; ++t) {
            pipe_wait(gd, 12u * (unsigned)(t + 1), gd_hi, (l < 2) ? 12u * (unsigned)t : 0u);
            proj_step(l, b0r, cq, Preg, mbuf, h16, Ast, (_Float16*)(LDSRAW + 65536), tid, xstore);
            pipe_sig(pd);
        }
    }
}

// ---------------- fallback: per-step kernels, c-state in global ----------------
__global__ __launch_bounds__(512)
void gate_fb(const _Float16* __restrict__ x16, const _Float16* __restrict__ Wfrag,
             const float* __restrict__ bias0, const float* __restrict__ bias1,
             const float* __restrict__ bias2,
             _Float16* __restrict__ h16, _Float16* __restrict__ mbuf,
             const _Float16* __restrict__ zerop, float* __restrict__ cfb, int s)
{
    __shared__ __align__(16) char LDSRAW[132096];
    _Float16* Ast  = (_Float16*)LDSRAW;
    float*    zstA = (float*)LDSRAW;
    float*    zstB = (float*)(LDSRAW + 65536);
    float*    bst  = (float*)(LDSRAW + 131072);
    const int tid = threadIdx.x, bid = blockIdx.x;
    const int ht = bid % 12, z = bid / 12, l = z % 3, bt2 = z / 3;
    const int t = s - l;
    if (t < 0 || t >= Tdim) return;
    const int wv = tid >> 6, lane = tid & 63;
    const int b0r = bt2 * 128, h0 = ht * 64;
    const int KC = (l == 0) ? 10 : 16;
    half8 Breg[16][2];
    load_Breg(Wfrag, l, ht, wv, lane, Breg);
    load_bst((l == 0) ? bias0 : (l == 1) ? bias1 : bias2, h0, tid, bst);
    __syncthreads();
    const int trow = tid >> 3, hcb = (tid & 7) * 8;
    float c[2][8];
#pragma unroll
    for (int p = 0; p < 2; ++p)
#pragma unroll
        for (int u = 0; u < 8; ++u)
            c[p][u] = cfb[((size_t)l * Bdim + b0r + p * 64 + trow) * Hdim + h0 + hcb + u];
    gate_step(l, b0r, h0, KC, t, Breg, c, x16, h16, zerop, mbuf, Ast, zstA, zstB, bst, tid);
#pragma unroll
    for (int p = 0; p < 2; ++p)
#pragma unroll
        for (int u = 0; u < 8; ++u)
            cfb[((size_t)l * Bdim + b0r + p * 64 + trow) * Hdim + h0 + hcb + u] = c[p][u];
}

__global__ __launch_bounds__(512)
void proj_fb(const _Float16* __restrict__ Pfrag, const _Float16* __restrict__ mbuf,
             _Float16* __restrict__ h16, int s)
{
    __shared__ __align__(16) char LDSRAW[131072];
    const int tid = threadIdx.x, bid = blockIdx.x;
    const int cq = bid & 3, z = bid >> 2, l = z % 3, bt2 = z / 3;
    const int tp = s - l;
    if (tp < 0 || tp >= Tdim) return;
    const int wv = tid >> 6, lane = tid & 63;
    half8 Preg[24];
    load_Preg(Pfrag, l, cq, wv, lane, Preg);
    proj_step(l, bt2 * 128, cq, Preg, mbuf, h16,
              (_Float16*)LDSRAW, (_Float16*)(LDSRAW + 65536), tid, false);
}

__global__ __launch_bounds__(512)
void fin_fb(const _Float16* __restrict__ h16, float* __restrict__ out)
{
    int row = blockIdx.x * 8 + (threadIdx.x >> 6);
    finalize_row(h16, out, row, threadIdx.x & 63);
}

extern "C" void kernel_launch(void* const* d_in, const int* in_sizes, int n_in,
                              void* d_out, int out_size, void* d_ws, size_t ws_size,
                              hipStream_t stream)
{
    (void)in_sizes; (void)n_in; (void)out_size; (void)ws_size;
    const float* x  = (const float*)d_in[0];
    const float* W0 = (const float*)d_in[1];
    const float* b0 = (const float*)d_in[2];
    const float* P0 = (const float*)d_in[3];
    const float* W1 = (const float*)d_in[4];
    const float* b1 = (const float*)d_in[5];
    const float* P1 = (const float*)d_in[6];
    const float* W2 = (const float*)d_in[7];
    const float* b2 = (const float*)d_in[8];
    const float* P2 = (const float*)d_in[9];

    char* ws = (char*)d_ws;
    _Float16* h16   = (_Float16*)(ws);
    _Float16* zerop = (_Float16*)(ws + ZP_OFF);
    _Float16* mbuf  = (_Float16*)(ws + MB_OFF);
    _Float16* x16   = (_Float16*)(ws + X_OFF);
    _Float16* Wfrag = (_Float16*)(ws + W_OFF);
    _Float16* Pfrag = (_Float16*)(ws + P_OFF);
    float*    cfb   = (float*)(ws + C_OFF);
    unsigned* flags = (unsigned*)(ws + C_OFF);   // coop path only; aliases cfb (fallback-only)
    float*    outp  = (float*)d_out;

    // zero h state + zero page (+ fallback c / pipe flags — same region)
    hipMemsetAsync(ws, 0, ZP_OFF + 256, stream);
    hipMemsetAsync(cfb, 0, C_BYTES, stream);

    {
        constexpr size_t total = W_HALFS + P_HALFS + X_HALFS;
        int grid = (int)((total + 255) / 256);
        repack_kernel<<<grid, 256, 0, stream>>>(x, W0, W1, W2, P0, P1, P2, Wfrag, Pfrag, x16);
    }

    int occ = 0;
    hipError_t oe = hipOccupancyMaxActiveBlocksPerMultiprocessor(&occ, lstm_persist, 512, 0);
    bool coop = (oe == hipSuccess && occ >= 1);
    if (coop) {
        void* args[] = { (void*)&x16, (void*)&Wfrag, (void*)&Pfrag,
                         (void*)&b0, (void*)&b1, (void*)&b2,
                         (void*)&h16, (void*)&mbuf, (void*)&zerop, (void*)&outp,
                         (void*)&flags };
        hipError_t le = hipLaunchCooperativeKernel((const void*)lstm_persist,
                                                   dim3(256), dim3(512), args, 0, stream);
        if (le != hipSuccess) { (void)hipGetLastError(); coop = false; }
    }
    if (!coop) {
        for (int s = 0; s < NSTEP; ++s) {
            gate_fb<<<180, 512, 0, stream>>>(x16, Wfrag, b0, b1, b2, h16, mbuf, zerop, cfb, s);
            proj_fb<<<60, 512, 0, stream>>>(Pfrag, mbuf, h16, s);
        }
        fin_fb<<<80, 512, 0, stream>>>(h16, outp);
    }
}

// Round 6
// 5139.876 us; speedup vs baseline: 1.4480x; 1.0016x over previous
//
#include <hip/hip_runtime.h>

#define Bdim 640
#define Hdim 768
#define PJdim 256
#define Tdim 160
#define NSTEP (Tdim + 2)
#define ZS 258   // zst row stride (floats): 256+2 spreads banks across rows

typedef _Float16 half8 __attribute__((ext_vector_type(8)));
typedef float floatx4 __attribute__((ext_vector_type(4)));

// ---------------- workspace layout (halfs/bytes) ----------------
constexpr size_t HB_HALFS = 3ull * Bdim * PJdim;            // 491,520
constexpr size_t ZP_OFF   = HB_HALFS * 2;                   // byte offset
constexpr size_t MB_OFF   = ZP_OFF + 256;
constexpr size_t MB_HALFS = 3ull * Bdim * Hdim;             // 1,474,560
constexpr size_t X_OFF    = MB_OFF + MB_HALFS * 2;
constexpr size_t X_HALFS  = (size_t)Tdim * Bdim * 40;       // 4,096,000
constexpr size_t W_OFF    = X_OFF + X_HALFS * 2;
constexpr size_t W_HALFS  = 36ull * 131072;                 // 4,718,592
constexpr size_t P_OFF    = W_OFF + W_HALFS * 2;
constexpr size_t P_HALFS  = 3ull * 196608;                  // 589,824
constexpr size_t C_OFF    = P_OFF + P_HALFS * 2;
constexpr size_t C_BYTES  = 3ull * Bdim * Hdim * 4;

__device__ __forceinline__ float sigm(float v) { return 1.0f / (1.0f + __expf(-v)); }
__device__ __forceinline__ float tanh_fast(float v) { return 2.0f / (1.0f + __expf(-2.0f * v)) - 1.0f; }

// Device-coherent 2B store (bypasses L1/L2). ONLY for cross-XCD h16 edges.
__device__ __forceinline__ void st_coh16b(void* p, _Float16 h) {
    union { _Float16 h; unsigned short u; } cv; cv.h = h;
    __hip_atomic_store((unsigned short*)p, cv.u, __ATOMIC_RELAXED, __HIP_MEMORY_SCOPE_AGENT);
}

// ---------------- fine-grained pipeline sync (R3 semantics, validated) ----------------
// Release: __syncthreads (vmcnt drain) + agent atomic add. Acquire: inv-only fence.
__device__ __forceinline__ void wait1(unsigned* c, unsigned tgt)
{
    if (threadIdx.x == 0) {
        while (__hip_atomic_load(c, __ATOMIC_RELAXED, __HIP_MEMORY_SCOPE_AGENT) < tgt)
            __builtin_amdgcn_s_sleep(1);
        __builtin_amdgcn_fence(__ATOMIC_ACQUIRE, "agent");   // buffer_inv, no wbl2
    }
    __syncthreads();
}

__device__ __forceinline__ void pipe_wait(unsigned* c0, unsigned t0, unsigned* c1, unsigned t1)
{
    if (threadIdx.x == 0) {
        if (t0)
            while (__hip_atomic_load(c0, __ATOMIC_RELAXED, __HIP_MEMORY_SCOPE_AGENT) < t0)
                __builtin_amdgcn_s_sleep(1);
        if (c1 && t1)
            while (__hip_atomic_load(c1, __ATOMIC_RELAXED, __HIP_MEMORY_SCOPE_AGENT) < t1)
                __builtin_amdgcn_s_sleep(1);
        __builtin_amdgcn_fence(__ATOMIC_ACQUIRE, "agent");
    }
    __syncthreads();
}

__device__ __forceinline__ void pipe_sig(unsigned* c)
{
    __syncthreads();                // drains vmcnt: stores visible at shared L2 / LLC
    if (threadIdx.x == 0)
        __hip_atomic_fetch_add(c, 1u, __ATOMIC_RELAXED, __HIP_MEMORY_SCOPE_AGENT);
}

// ---------------- one-time repack: fragment-ordered fp16 images (unchanged) ----------------
__global__ void repack_kernel(const float* __restrict__ x,
                              const float* __restrict__ W0, const float* __restrict__ W1,
                              const float* __restrict__ W2, const float* __restrict__ P0,
                              const float* __restrict__ P1, const float* __restrict__ P2,
                              _Float16* __restrict__ Wfrag, _Float16* __restrict__ Pfrag,
                              _Float16* __restrict__ x16)
{
    size_t idx = (size_t)blockIdx.x * 256 + threadIdx.x;
    if (idx < W_HALFS) {
        int slab = (int)(idx >> 17);          // /131072
        int l = slab / 12, ht = slab % 12;
        int r  = (int)(idx & 131071);
        int kc = r >> 13;                      // /8192
        int r2 = r & 8191;
        int g  = r2 >> 11;
        int cf = (r2 >> 9) & 3;
        int u  = r2 & 511;
        int lane = u >> 3, e = u & 7;
        int qd = lane >> 4, ln = lane & 15;
        int k   = kc * 32 + qd * 8 + e;
        int col = g * Hdim + ht * 64 + cf * 16 + ln;
        float v;
        if (l == 0)      v = (k < 296) ? W0[(size_t)k * 3072 + col] : 0.0f;
        else if (l == 1) v = W1[(size_t)k * 3072 + col];
        else             v = W2[(size_t)k * 3072 + col];
        Wfrag[idx] = (_Float16)v;
    } else if (idx < W_HALFS + P_HALFS) {
        size_t i = idx - W_HALFS;
        int l = (int)(i / 196608);
        int r = (int)(i % 196608);
        int cq = r / 49152;
        int r2 = r % 49152;
        int kc = r2 / 2048;
        int r3 = r2 & 2047;
        int cgr = r3 >> 9;
        int u  = r3 & 511;
        int lane = u >> 3, e = u & 7;
        int qd = lane >> 4, ln = lane & 15;
        int k  = kc * 32 + qd * 8 + e;
        int pj = cq * 64 + cgr * 16 + ln;
        const float* P = (l == 0) ? P0 : (l == 1) ? P1 : P2;
        Pfrag[i] = (_Float16)P[(size_t)k * PJdim + pj];
    } else if (idx < W_HALFS + P_HALFS + X_HALFS) {
        size_t i = idx - W_HALFS - P_HALFS;
        x16[i] = (_Float16)x[i];
    }
}

// ---------------- gate step: split-wait staging + 2-barrier elementwise ----------------
// block: 128 rows x (4 gates x 64 hcols); 8 waves; wave (g,hh) owns 128x32 of gate g.
// Staging: 2-kc chunks, 4-slot LDS ring (32KB, aliases zst), 1 barrier/chunk, 1-ahead
// vector loads (R3-proven path). For l>0 the own-recurrence half (kc8..15, h(l,t-1))
// is staged+GEMM'd under pd>=4t BEFORE waiting on the lower layer (pd_lo>=4(t+1)).
// Elementwise: full 128x256 z-tile in zst (stride ZS), ONE barrier, each thread
// computes (row=tid>>2, 16 cols) -> 2 uint4 mbuf stores. Was 16 barriers, now 2.
__device__ __forceinline__ void gate_step(
    int l, int b0r, int h0, int t,
    const half8 (&Breg)[16][2], float (&c)[16],
    const _Float16* __restrict__ x16, const _Float16* __restrict__ h16,
    const _Float16* __restrict__ zerop, _Float16* __restrict__ mbuf,
    _Float16* __restrict__ Ast, float* __restrict__ zst, const float* __restrict__ bst,
    unsigned* pd, unsigned pdt, unsigned* pdlo, unsigned pdlot, int tid)
{
    const int wv = tid >> 6, lane = tid & 63, qd = lane >> 4, ln = lane & 15;
    const int g = wv >> 1, hh = wv & 1;
    const int qd8 = qd * 8;
    const int rowg = b0r + wv * 16 + ln;                    // staging row for this lane

    const _Float16* xt  = x16 + ((size_t)t * Bdim + rowg) * 40;
    const _Float16* h0b = h16 + (size_t)rowg * PJdim - 40;                       // l==0, k in [40,296)
    const _Float16* lob = (l > 0) ? h16 + ((size_t)(l - 1) * Bdim + rowg) * PJdim : nullptr;
    const _Float16* hib = h16 + ((size_t)l * Bdim + rowg) * PJdim - 256;         // l>0, k>=256

    auto srcp = [&](int kc) -> const _Float16* {
        int k = kc * 32 + qd8;
        if (l == 0) return (k < 40) ? xt + k : (k < 296) ? h0b + k : zerop;
        return (k < 256) ? lob + k : hib + k;
    };

    floatx4 acc[8][2];
    const floatx4 fz = {0.f, 0.f, 0.f, 0.f};
#pragma unroll
    for (int i = 0; i < 8; ++i) { acc[i][0] = fz; acc[i][1] = fz; }

    _Float16* Aw = Ast + wv * 512 + lane * 8;

    auto stage_gemm = [&](int kc0, int nkc) {
        const int ncp = nkc >> 1;                      // 2-kc chunks
        uint4 p0 = *(const uint4*)srcp(kc0);
        uint4 p1 = *(const uint4*)srcp(kc0 + 1);
#pragma unroll
        for (int cp = 0; cp < 5; ++cp) {
            if (cp < ncp) {
                const int s0 = (cp & 1) * 2;           // 4-slot ring: {0,1} / {2,3}
                *(uint4*)(Aw + (size_t)s0 * 4096)       = p0;
                *(uint4*)(Aw + (size_t)(s0 + 1) * 4096) = p1;
                if (cp + 1 < ncp) {
                    p0 = *(const uint4*)srcp(kc0 + 2 * cp + 2);
                    p1 = *(const uint4*)srcp(kc0 + 2 * cp + 3);
                }
                __syncthreads();                       // chunk staged; ring WAR covered
#pragma unroll
                for (int j = 0; j < 2; ++j) {
                    const _Float16* Ab = Ast + (size_t)(s0 + j) * 4096;
                    const int kc = kc0 + 2 * cp + j;
#pragma unroll
                    for (int rf = 0; rf < 8; ++rf) {
                        half8 af = *(const half8*)(Ab + rf * 512 + lane * 8);
                        acc[rf][0] = __builtin_amdgcn_mfma_f32_16x16x32_f16(af, Breg[kc][0], acc[rf][0], 0, 0, 0);
                        acc[rf][1] = __builtin_amdgcn_mfma_f32_16x16x32_f16(af, Breg[kc][1], acc[rf][1], 0, 0, 0);
                    }
                }
            }
        }
    };

    if (pd) wait1(pd, pdt);                            // own h(l,t-1) + mbuf WAR
    if (l == 0) {
        stage_gemm(0, 10);
    } else {
        stage_gemm(8, 8);                              // own-recurrence half first
        if (pdlo) wait1(pdlo, pdlot);                  // lower layer h(l-1,t)
        stage_gemm(0, 8);
    }
    __syncthreads();                                   // last MFMA reads done; zst aliases ring

    // ---- z write-all (one pass, no per-slice barriers)
#pragma unroll
    for (int rf = 0; rf < 8; ++rf)
#pragma unroll
        for (int cf = 0; cf < 2; ++cf)
#pragma unroll
            for (int r = 0; r < 4; ++r)
                zst[(size_t)(rf * 16 + qd * 4 + r) * ZS + g * 64 + hh * 32 + cf * 16 + ln]
                    = acc[rf][cf][r];
    __syncthreads();

    // ---- elementwise: thread owns (row, 16 cols)
    const int row = tid >> 2, c0 = (tid & 3) * 16;
    const float* zrow = zst + (size_t)row * ZS;
    union { _Float16 h[16]; uint4 v[2]; } pk;
#pragma unroll
    for (int q = 0; q < 4; ++q) {
        const int o = q * 4;
        float4 zi = *(const float4*)(zrow + c0 + o);
        float4 zj = *(const float4*)(zrow + 64 + c0 + o);
        float4 zf = *(const float4*)(zrow + 128 + c0 + o);
        float4 zo = *(const float4*)(zrow + 192 + c0 + o);
        float4 bi = *(const float4*)(bst + c0 + o);
        float4 bj = *(const float4*)(bst + 64 + c0 + o);
        float4 bf = *(const float4*)(bst + 128 + c0 + o);
        float4 bo = *(const float4*)(bst + 192 + c0 + o);
        float cn0 = sigm(zf.x + bf.x) * c[o + 0] + sigm(zi.x + bi.x) * tanh_fast(zj.x + bj.x);
        float cn1 = sigm(zf.y + bf.y) * c[o + 1] + sigm(zi.y + bi.y) * tanh_fast(zj.y + bj.y);
        float cn2 = sigm(zf.z + bf.z) * c[o + 2] + sigm(zi.z + bi.z) * tanh_fast(zj.z + bj.z);
        float cn3 = sigm(zf.w + bf.w) * c[o + 3] + sigm(zi.w + bi.w) * tanh_fast(zj.w + bj.w);
        c[o + 0] = cn0; c[o + 1] = cn1; c[o + 2] = cn2; c[o + 3] = cn3;
        pk.h[o + 0] = (_Float16)(sigm(zo.x + bo.x) * tanh_fast(cn0));
        pk.h[o + 1] = (_Float16)(sigm(zo.y + bo.y) * tanh_fast(cn1));
        pk.h[o + 2] = (_Float16)(sigm(zo.z + bo.z) * tanh_fast(cn2));
        pk.h[o + 3] = (_Float16)(sigm(zo.w + bo.w) * tanh_fast(cn3));
    }
    _Float16* mb = mbuf + ((size_t)l * Bdim + b0r + row) * Hdim + h0 + c0;
    *(uint4*)mb       = pk.v[0];
    *(uint4*)(mb + 8) = pk.v[1];
}

// ---------------- proj step: 6 chunks of 4 kc, 2x32KB dbuf, 1 barrier/chunk ----------------
__device__ __forceinline__ void proj_step(
    int l, int b0r, int cq, const half8 (&Preg)[24],
    const _Float16* __restrict__ mbuf, _Float16* __restrict__ h16,
    _Float16* __restrict__ AstA, _Float16* __restrict__ AstB, int tid, bool xstore)
{
    const int wv = tid >> 6, lane = tid & 63, qd = lane >> 4, ln = lane & 15;
    const int rh = wv >> 2, cgi = wv & 3;
    const int rowg = b0r + wv * 16 + ln;
    const _Float16* mrow = mbuf + ((size_t)l * Bdim + rowg) * Hdim + qd * 8;
    _Float16* wA = AstA + wv * 512 + lane * 8;
    _Float16* wB = AstB + wv * 512 + lane * 8;

    floatx4 pacc[4];
    const floatx4 fz = {0.f, 0.f, 0.f, 0.f};
#pragma unroll
    for (int i = 0; i < 4; ++i) pacc[i] = fz;

    uint4 p0 = *(const uint4*)(mrow);
    uint4 p1 = *(const uint4*)(mrow + 32);
    uint4 p2 = *(const uint4*)(mrow + 64);
    uint4 p3 = *(const uint4*)(mrow + 96);
#pragma unroll
    for (int ch = 0; ch < 6; ++ch) {
        _Float16* W = (ch & 1) ? wB : wA;
        const _Float16* R = (ch & 1) ? AstB : AstA;
        *(uint4*)(W)                      = p0;
        *(uint4*)(W + (size_t)1 * 4096)   = p1;
        *(uint4*)(W + (size_t)2 * 4096)   = p2;
        *(uint4*)(W + (size_t)3 * 4096)   = p3;
        if (ch < 5) {
            p0 = *(const uint4*)(mrow + (4 * ch + 4) * 32);
            p1 = *(const uint4*)(mrow + (4 * ch + 5) * 32);
            p2 = *(const uint4*)(mrow + (4 * ch + 6) * 32);
            p3 = *(const uint4*)(mrow + (4 * ch + 7) * 32);
        }
        __syncthreads();                  // chunk staged; dbuf WAR covered (1 barrier gap)
#pragma unroll
        for (int kk = 0; kk < 4; ++kk) {
            const _Float16* Ab = R + (size_t)kk * 4096;
#pragma unroll
            for (int rfl = 0; rfl < 4; ++rfl) {
                half8 af = *(const half8*)(Ab + (rh * 4 + rfl) * 512 + lane * 8);
                pacc[rfl] = __builtin_amdgcn_mfma_f32_16x16x32_f16(af, Preg[ch * 4 + kk], pacc[rfl], 0, 0, 0);
            }
        }
    }

    if (xstore) {
#pragma unroll
        for (int rfl = 0; rfl < 4; ++rfl)
#pragma unroll
            for (int r = 0; r < 4; ++r) {
                int row = b0r + (rh * 4 + rfl) * 16 + qd * 4 + r;
                st_coh16b(h16 + ((size_t)l * Bdim + row) * PJdim + cq * 64 + cgi * 16 + ln,
                          (_Float16)pacc[rfl][r]);
            }
    } else {
#pragma unroll
        for (int rfl = 0; rfl < 4; ++rfl)
#pragma unroll
            for (int r = 0; r < 4; ++r) {
                int row = b0r + (rh * 4 + rfl) * 16 + qd * 4 + r;
                h16[((size_t)l * Bdim + row) * PJdim + cq * 64 + cgi * 16 + ln] = (_Float16)pacc[rfl][r];
            }
    }
}

__device__ __forceinline__ void load_Breg(const _Float16* __restrict__ Wfrag, int l, int ht,
                                          int wv, int lane, half8 (&Breg)[16][2])
{
    const int g = wv >> 1, hh = wv & 1;
    const _Float16* wslab = Wfrag + ((size_t)(l * 12 + ht)) * 131072;
#pragma unroll
    for (int kc = 0; kc < 16; ++kc)
#pragma unroll
        for (int cf = 0; cf < 2; ++cf)
            Breg[kc][cf] = *(const half8*)(wslab + kc * 8192 + g * 2048 + (hh * 2 + cf) * 512 + lane * 8);
}

__device__ __forceinline__ void load_Preg(const _Float16* __restrict__ Pfrag, int l, int cq,
                                          int wv, int lane, half8 (&Preg)[24])
{
    const int cgi = wv & 3;
    const _Float16* pslab = Pfrag + (size_t)l * 196608 + (size_t)cq * 49152;
#pragma unroll
    for (int kc = 0; kc < 24; ++kc)
        Preg[kc] = *(const half8*)(pslab + kc * 2048 + cgi * 512 + lane * 8);
}

__device__ __forceinline__ void load_bst(const float* __restrict__ bias, int h0, int tid,
                                         float* __restrict__ bst)
{
    if (tid < 256) {
        int gg = tid >> 6, u = tid & 63;
        bst[tid] = bias[gg * Hdim + h0 + u] + ((gg == 2) ? 1.0f : 0.0f);  // forget bias folded
    }
}

__device__ __forceinline__ void finalize_row(const _Float16* __restrict__ h16,
                                             float* __restrict__ out, int row, int lane)
{
    const _Float16* e = h16 + ((size_t)2 * Bdim + row) * PJdim + lane * 4;
    float v0 = (float)e[0], v1 = (float)e[1], v2 = (float)e[2], v3 = (float)e[3];
    float ss = v0 * v0 + v1 * v1 + v2 * v2 + v3 * v3;
#pragma unroll
    for (int o = 32; o > 0; o >>= 1) ss += __shfl_xor(ss, o, 64);
    float rs = rsqrtf(fmaxf(ss, 1e-12f));
    float4 o4; o4.x = v0 * rs; o4.y = v1 * rs; o4.z = v2 * rs; o4.w = v3 * rs;
    *(float4*)(out + (size_t)row * PJdim + lane * 4) = o4;
}

// ---------------- persistent kernel: flag-pipelined, barrier-minimal bodies ----------------
// Hazard/DAG audit identical to R3 (counters count completed steps):
//  gate(l,t): pd[gid]>=4t (own h + mbuf WAR), pd[gid-1]>=4(t+1) (lower h) [split-waited]
//  proj(l,t): gd[gid]>=12(t+1) (m ready + h16 read WAR), gd[gid+1]>=12t (h16 WAR, l<2)
// LDS map (133KB -> 1 block/CU):
//  gate: ring 4x8KB at [0,32K) aliases zst; zst 128xZSx4 = 132,096B at [0,...);
//        bst 1KB at 132096. Aliasing safe: z-writes only after post-GEMM barrier.
//  proj: AstA [0,32K), AstB [32K,64K).
__global__ __launch_bounds__(512)
void lstm_persist(const _Float16* __restrict__ x16, const _Float16* __restrict__ Wfrag,
                  const _Float16* __restrict__ Pfrag,
                  const float* __restrict__ bias0, const float* __restrict__ bias1,
                  const float* __restrict__ bias2,
                  _Float16* __restrict__ h16, _Float16* __restrict__ mbuf,
                  const _Float16* __restrict__ zerop, float* __restrict__ out,
                  unsigned* __restrict__ flags)
{
    __shared__ __align__(16) char LDSRAW[133120];
    _Float16* Ast  = (_Float16*)LDSRAW;
    float*    zst  = (float*)LDSRAW;
    float*    bst  = (float*)(LDSRAW + 132096);

    const int tid = threadIdx.x, bid = blockIdx.x;
    const int wv = tid >> 6, lane = tid & 63;

    // XCD-grouped role mapping: gid lives on XCD gid>>1 (assuming bid%8=XCD)
    const int xcd = bid & 7, slot = bid >> 3;
    const int gid = xcd * 2 + (slot >> 4);
    const int rr  = slot & 15;
    if (gid >= 15) return;                              // 16 idle blocks exit
    const int bt2 = gid / 3, l = gid % 3;
    const int b0r = bt2 * 128;

    unsigned* gd = flags + (size_t)gid * 64;            // 256B-spread counters
    unsigned* pd = gd + 32;

    if (rr < 12) {                                      // ---- gate block ----
        const int ht = rr, h0 = ht * 64;
        half8 Breg[16][2];
        load_Breg(Wfrag, l, ht, wv, lane, Breg);
        load_bst((l == 0) ? bias0 : (l == 1) ? bias1 : bias2, h0, tid, bst);
        float c[16];
#pragma unroll
        for (int u = 0; u < 16; ++u) c[u] = 0.f;
        unsigned* pd_lo = (l > 0) ? flags + (size_t)(gid - 1) * 64 + 32 : nullptr;
        for (int t = 0; t < Tdim; ++t) {
            gate_step(l, b0r, h0, t, Breg, c, x16, h16, zerop, mbuf,
                      Ast, zst, bst,
                      pd, 4u * (unsigned)t,
                      pd_lo, (l > 0) ? 4u * (unsigned)(t + 1) : 0u, tid);
            pipe_sig(gd);
        }
        if (l == 2 && rr < 8) {                         // finalize: 8 blocks x 16 rows per gid
            wait1(pd, 4u * (unsigned)Tdim);
            int row0 = b0r + rr * 16 + wv * 2;
            finalize_row(h16, out, row0, lane);
            finalize_row(h16, out, row0 + 1, lane);
        }
    } else {                                            // ---- proj block ----
        const int cq = rr - 12;
        const bool xstore = ((gid & 1) == 1) && (gid + 1 < 15) && ((gid + 1) % 3 != 0);
        half8 Preg[24];
        load_Preg(Pfrag, l, cq, wv, lane, Preg);
        unsigned* gd_hi = (l < 2) ? flags + (size_t)(gid + 1) * 64 : nullptr;
        for (int t = 0; t < Tdim; ++t) {
            pipe_wait(gd, 12u * (unsigned)(t + 1), gd_hi, (l < 2) ? 12u * (unsigned)t : 0u);
            proj_step(l, b0r, cq, Preg, mbuf, h16,
                      Ast, (_Float16*)(LDSRAW + 32768), tid, xstore);
            pipe_sig(pd);
        }
    }
}

// ---------------- fallback: per-step kernels, c-state in global ----------------
__global__ __launch_bounds__(512)
void gate_fb(const _Float16* __restrict__ x16, const _Float16* __restrict__ Wfrag,
             const float* __restrict__ bias0, const float* __restrict__ bias1,
             const float* __restrict__ bias2,
             _Float16* __restrict__ h16, _Float16* __restrict__ mbuf,
             const _Float16* __restrict__ zerop, float* __restrict__ cfb, int s)
{
    __shared__ __align__(16) char LDSRAW[133120];
    _Float16* Ast  = (_Float16*)LDSRAW;
    float*    zst  = (float*)LDSRAW;
    float*    bst  = (float*)(LDSRAW + 132096);
    const int tid = threadIdx.x, bid = blockIdx.x;
    const int ht = bid % 12, z = bid / 12, l = z % 3, bt2 = z / 3;
    const int t = s - l;
    if (t < 0 || t >= Tdim) return;
    const int wv = tid >> 6, lane = tid & 63;
    const int b0r = bt2 * 128, h0 = ht * 64;
    half8 Breg[16][2];
    load_Breg(Wfrag, l, ht, wv, lane, Breg);
    load_bst((l == 0) ? bias0 : (l == 1) ? bias1 : bias2, h0, tid, bst);
    __syncthreads();
    const int row = tid >> 2, c0 = (tid & 3) * 16;
    float c[16];
#pragma unroll
    for (int u = 0; u < 16; ++u)
        c[u] = cfb[((size_t)l * Bdim + b0r + row) * Hdim + h0 + c0 + u];
    gate_step(l, b0r, h0, t, Breg, c, x16, h16, zerop, mbuf, Ast, zst, bst,
              nullptr, 0u, nullptr, 0u, tid);
#pragma unroll
    for (int u = 0; u < 16; ++u)
        cfb[((size_t)l * Bdim + b0r + row) * Hdim + h0 + c0 + u] = c[u];
}

__global__ __launch_bounds__(512)
void proj_fb(const _Float16* __restrict__ Pfrag, const _Float16* __restrict__ mbuf,
             _Float16* __restrict__ h16, int s)
{
    __shared__ __align__(16) char LDSRAW[65536];
    const int tid = threadIdx.x, bid = blockIdx.x;
    const int cq = bid & 3, z = bid >> 2, l = z % 3, bt2 = z / 3;
    const int tp = s - l;
    if (tp < 0 || tp >= Tdim) return;
    const int wv = tid >> 6, lane = tid & 63;
    half8 Preg[24];
    load_Preg(Pfrag, l, cq, wv, lane, Preg);
    proj_step(l, bt2 * 128, cq, Preg, mbuf, h16,
              (_Float16*)LDSRAW, (_Float16*)(LDSRAW + 32768), tid, false);
}

__global__ __launch_bounds__(512)
void fin_fb(const _Float16* __restrict__ h16, float* __restrict__ out)
{
    int row = blockIdx.x * 8 + (threadIdx.x >> 6);
    finalize_row(h16, out, row, threadIdx.x & 63);
}

extern "C" void kernel_launch(void* const* d_in, const int* in_sizes, int n_in,
                              void* d_out, int out_size, void* d_ws, size_t ws_size,
                              hipStream_t stream)
{
    (void)in_sizes; (void)n_in; (void)out_size; (void)ws_size;
    const float* x  = (const float*)d_in[0];
    const float* W0 = (const float*)d_in[1];
    const float* b0 = (const float*)d_in[2];
    const float* P0 = (const float*)d_in[3];
    const float* W1 = (const float*)d_in[4];
    const float* b1 = (const float*)d_in[5];
    const float* P1 = (const float*)d_in[6];
    const float* W2 = (const float*)d_in[7];
    const float* b2 = (const float*)d_in[8];
    const float* P2 = (const float*)d_in[9];

    char* ws = (char*)d_ws;
    _Float16* h16   = (_Float16*)(ws);
    _Float16* zerop = (_Float16*)(ws + ZP_OFF);
    _Float16* mbuf  = (_Float16*)(ws + MB_OFF);
    _Float16* x16   = (_Float16*)(ws + X_OFF);
    _Float16* Wfrag = (_Float16*)(ws + W_OFF);
    _Float16* Pfrag = (_Float16*)(ws + P_OFF);
    float*    cfb   = (float*)(ws + C_OFF);
    unsigned* flags = (unsigned*)(ws + C_OFF);   // coop path only; aliases cfb (fallback-only)
    float*    outp  = (float*)d_out;

    // zero h state + zero page (+ fallback c / pipe flags — same region)
    hipMemsetAsync(ws, 0, ZP_OFF + 256, stream);
    hipMemsetAsync(cfb, 0, C_BYTES, stream);

    {
        constexpr size_t total = W_HALFS + P_HALFS + X_HALFS;
        int grid = (int)((total + 255) / 256);
        repack_kernel<<<grid, 256, 0, stream>>>(x, W0, W1, W2, P0, P1, P2, Wfrag, Pfrag, x16);
    }

    int occ = 0;
    hipError_t oe = hipOccupancyMaxActiveBlocksPerMultiprocessor(&occ, lstm_persist, 512, 0);
    bool coop = (oe == hipSuccess && occ >= 1);
    if (coop) {
        void* args[] = { (void*)&x16, (void*)&Wfrag, (void*)&Pfrag,
                         (void*)&b0, (void*)&b1, (void*)&b2,
                         (void*)&h16, (void*)&mbuf, (void*)&zerop, (void*)&outp,
                         (void*)&flags };
        hipError_t le = hipLaunchCooperativeKernel((const void*)lstm_persist,
                                                   dim3(256), dim3(512), args, 0, stream);
        if (le != hipSuccess) { (void)hipGetLastError(); coop = false; }
    }
    if (!coop) {
        for (int s = 0; s < NSTEP; ++s) {
            gate_fb<<<180, 512, 0, stream>>>(x16, Wfrag, b0, b1, b2, h16, mbuf, zerop, cfb, s);
            proj_fb<<<60, 512, 0, stream>>>(Pfrag, mbuf, h16, s);
        }
        fin_fb<<<80, 512, 0, stream>>>(h16, outp);
    }
}

// Round 7
// 5138.305 us; speedup vs baseline: 1.4484x; 1.0003x over previous
//
#include <hip/hip_runtime.h>

#define Bdim 640
#define Hdim 768
#define PJdim 256
#define Tdim 160
#define NSTEP (Tdim + 2)
#define ZS 258   // zst row stride (floats)

typedef _Float16 half8 __attribute__((ext_vector_type(8)));
typedef float floatx4 __attribute__((ext_vector_type(4)));

// ---------------- workspace layout (halfs/bytes) ----------------
constexpr size_t HB_HALFS = 3ull * Bdim * PJdim;            // 491,520
constexpr size_t ZP_OFF   = HB_HALFS * 2;                   // byte offset
constexpr size_t MB_OFF   = ZP_OFF + 256;
constexpr size_t MB_HALFS = 3ull * Bdim * Hdim;             // 1,474,560
constexpr size_t X_OFF    = MB_OFF + MB_HALFS * 2;
constexpr size_t X_HALFS  = (size_t)Tdim * Bdim * 40;       // 4,096,000
constexpr size_t W_OFF    = X_OFF + X_HALFS * 2;
constexpr size_t W_HALFS  = 36ull * 131072;                 // 4,718,592
constexpr size_t P_OFF    = W_OFF + W_HALFS * 2;
constexpr size_t P_HALFS  = 3ull * 196608;                  // 589,824
constexpr size_t C_OFF    = P_OFF + P_HALFS * 2;
constexpr size_t C_BYTES  = 3ull * Bdim * Hdim * 4;

__device__ __forceinline__ float sigm(float v) { return 1.0f / (1.0f + __expf(-v)); }
__device__ __forceinline__ float tanh_fast(float v) { return 2.0f / (1.0f + __expf(-2.0f * v)) - 1.0f; }

// Device-coherent 16B load (sc0+sc1: bypass L1/L2, served from LLC).
// ONLY for the 5 cross-XCD h16 consumer edges (even gid, l>0 reading h(l-1)).
__device__ __forceinline__ uint4 ld_coh16(const void* p) {
    const unsigned long long* q = (const unsigned long long*)p;
    unsigned long long a = __hip_atomic_load(q,     __ATOMIC_RELAXED, __HIP_MEMORY_SCOPE_AGENT);
    unsigned long long b = __hip_atomic_load(q + 1, __ATOMIC_RELAXED, __HIP_MEMORY_SCOPE_AGENT);
    uint4 r; r.x = (unsigned)a; r.y = (unsigned)(a >> 32);
    r.z = (unsigned)b; r.w = (unsigned)(b >> 32);
    return r;
}
// Device-coherent 2B store (to LLC). ONLY for cross-XCD h16 producer edges.
__device__ __forceinline__ void st_coh16b(void* p, _Float16 h) {
    union { _Float16 h; unsigned short u; } cv; cv.h = h;
    __hip_atomic_store((unsigned short*)p, cv.u, __ATOMIC_RELAXED, __HIP_MEMORY_SCOPE_AGENT);
}

// ---------------- fine-grained pipeline sync ----------------
// KEY CHANGE (R7): acquire = buffer_inv sc0 (per-CU 32KB L1 flash-inv, cheap)
// instead of fence(acquire,agent) = buffer_inv sc1 (full 4MB XCD-L2 invalidate).
// Why sound: CDNA vector L1 is write-through -> same-XCD producers' stores are
// already IN the shared L2 when their flag lands (vmcnt drained at pipe_sig's
// __syncthreads). Only the consumer's private L1 can be stale -> sc0 inv covers
// it. Cross-XCD edges don't rely on L2 at all: producer stores sc0+sc1 (LLC),
// consumer reads agent-scope (LLC). The sc1 L2-inv executed 1-2x per block-step
// was the one mechanism common to ALL of R0-R6 (~30us/step invariant).
// Placement: non-tid0 threads inv BEFORE the barrier (they read nothing between
// inv and barrier-release, so early inv is safe); tid0 invs after its spin.
__device__ __forceinline__ void wait1(unsigned* c, unsigned tgt)
{
    if (threadIdx.x == 0) {
        while (__hip_atomic_load(c, __ATOMIC_RELAXED, __HIP_MEMORY_SCOPE_AGENT) < tgt)
            __builtin_amdgcn_s_sleep(1);
    }
    asm volatile("buffer_inv sc0" ::: "memory");   // L1-only invalidate
    __syncthreads();
}

__device__ __forceinline__ void pipe_wait(unsigned* c0, unsigned t0, unsigned* c1, unsigned t1)
{
    if (threadIdx.x == 0) {
        if (t0)
            while (__hip_atomic_load(c0, __ATOMIC_RELAXED, __HIP_MEMORY_SCOPE_AGENT) < t0)
                __builtin_amdgcn_s_sleep(1);
        if (c1 && t1)
            while (__hip_atomic_load(c1, __ATOMIC_RELAXED, __HIP_MEMORY_SCOPE_AGENT) < t1)
                __builtin_amdgcn_s_sleep(1);
    }
    asm volatile("buffer_inv sc0" ::: "memory");   // L1-only invalidate
    __syncthreads();
}

__device__ __forceinline__ void pipe_sig(unsigned* c)
{
    __syncthreads();                // drains vmcnt: write-through stores are in L2/LLC
    if (threadIdx.x == 0)
        __hip_atomic_fetch_add(c, 1u, __ATOMIC_RELAXED, __HIP_MEMORY_SCOPE_AGENT);
}

// ---------------- one-time repack: fragment-ordered fp16 images (unchanged) ----------------
__global__ void repack_kernel(const float* __restrict__ x,
                              const float* __restrict__ W0, const float* __restrict__ W1,
                              const float* __restrict__ W2, const float* __restrict__ P0,
                              const float* __restrict__ P1, const float* __restrict__ P2,
                              _Float16* __restrict__ Wfrag, _Float16* __restrict__ Pfrag,
                              _Float16* __restrict__ x16)
{
    size_t idx = (size_t)blockIdx.x * 256 + threadIdx.x;
    if (idx < W_HALFS) {
        int slab = (int)(idx >> 17);          // /131072
        int l = slab / 12, ht = slab % 12;
        int r  = (int)(idx & 131071);
        int kc = r >> 13;                      // /8192
        int r2 = r & 8191;
        int g  = r2 >> 11;
        int cf = (r2 >> 9) & 3;
        int u  = r2 & 511;
        int lane = u >> 3, e = u & 7;
        int qd = lane >> 4, ln = lane & 15;
        int k   = kc * 32 + qd * 8 + e;
        int col = g * Hdim + ht * 64 + cf * 16 + ln;
        float v;
        if (l == 0)      v = (k < 296) ? W0[(size_t)k * 3072 + col] : 0.0f;
        else if (l == 1) v = W1[(size_t)k * 3072 + col];
        else             v = W2[(size_t)k * 3072 + col];
        Wfrag[idx] = (_Float16)v;
    } else if (idx < W_HALFS + P_HALFS) {
        size_t i = idx - W_HALFS;
        int l = (int)(i / 196608);
        int r = (int)(i % 196608);
        int cq = r / 49152;
        int r2 = r % 49152;
        int kc = r2 / 2048;
        int r3 = r2 & 2047;
        int cgr = r3 >> 9;
        int u  = r3 & 511;
        int lane = u >> 3, e = u & 7;
        int qd = lane >> 4, ln = lane & 15;
        int k  = kc * 32 + qd * 8 + e;
        int pj = cq * 64 + cgr * 16 + ln;
        const float* P = (l == 0) ? P0 : (l == 1) ? P1 : P2;
        Pfrag[i] = (_Float16)P[(size_t)k * PJdim + pj];
    } else if (idx < W_HALFS + P_HALFS + X_HALFS) {
        size_t i = idx - W_HALFS - P_HALFS;
        x16[i] = (_Float16)x[i];
    }
}

// ---------------- gate step (R6 body, + coherent-lob path for cross-XCD gids) ----------------
__device__ __forceinline__ void gate_step(
    int l, int b0r, int h0, int t, bool xl,
    const half8 (&Breg)[16][2], float (&c)[16],
    const _Float16* __restrict__ x16, const _Float16* __restrict__ h16,
    const _Float16* __restrict__ zerop, _Float16* __restrict__ mbuf,
    _Float16* __restrict__ Ast, float* __restrict__ zst, const float* __restrict__ bst,
    unsigned* pd, unsigned pdt, unsigned* pdlo, unsigned pdlot, int tid)
{
    const int wv = tid >> 6, lane = tid & 63, qd = lane >> 4, ln = lane & 15;
    const int g = wv >> 1, hh = wv & 1;
    const int qd8 = qd * 8;
    const int rowg = b0r + wv * 16 + ln;                    // staging row for this lane

    const _Float16* xt  = x16 + ((size_t)t * Bdim + rowg) * 40;
    const _Float16* h0b = h16 + (size_t)rowg * PJdim - 40;                       // l==0, k in [40,296)
    const _Float16* lob = (l > 0) ? h16 + ((size_t)(l - 1) * Bdim + rowg) * PJdim : nullptr;
    const _Float16* hib = h16 + ((size_t)l * Bdim + rowg) * PJdim - 256;         // l>0, k>=256

    auto srcp = [&](int kc) -> const _Float16* {
        int k = kc * 32 + qd8;
        if (l == 0) return (k < 40) ? xt + k : (k < 296) ? h0b + k : zerop;
        return (k < 256) ? lob + k : hib + k;
    };

    floatx4 acc[8][2];
    const floatx4 fz = {0.f, 0.f, 0.f, 0.f};
#pragma unroll
    for (int i = 0; i < 8; ++i) { acc[i][0] = fz; acc[i][1] = fz; }

    _Float16* Aw = Ast + wv * 512 + lane * 8;

    // coh=true: these kc-slices read h(l-1) produced on ANOTHER XCD -> stale
    // clean lines may sit in our L2 -> must read device-coherent (LLC).
    auto stage_gemm = [&](int kc0, int nkc, bool coh) {
        const int ncp = nkc >> 1;                      // 2-kc chunks
        uint4 p0 = coh ? ld_coh16(srcp(kc0))     : *(const uint4*)srcp(kc0);
        uint4 p1 = coh ? ld_coh16(srcp(kc0 + 1)) : *(const uint4*)srcp(kc0 + 1);
#pragma unroll
        for (int cp = 0; cp < 5; ++cp) {
            if (cp < ncp) {
                const int s0 = (cp & 1) * 2;           // 4-slot ring: {0,1} / {2,3}
                *(uint4*)(Aw + (size_t)s0 * 4096)       = p0;
                *(uint4*)(Aw + (size_t)(s0 + 1) * 4096) = p1;
                if (cp + 1 < ncp) {
                    p0 = coh ? ld_coh16(srcp(kc0 + 2 * cp + 2)) : *(const uint4*)srcp(kc0 + 2 * cp + 2);
                    p1 = coh ? ld_coh16(srcp(kc0 + 2 * cp + 3)) : *(const uint4*)srcp(kc0 + 2 * cp + 3);
                }
                __syncthreads();                       // chunk staged; ring WAR covered
#pragma unroll
                for (int j = 0; j < 2; ++j) {
                    const _Float16* Ab = Ast + (size_t)(s0 + j) * 4096;
                    const int kc = kc0 + 2 * cp + j;
#pragma unroll
                    for (int rf = 0; rf < 8; ++rf) {
                        half8 af = *(const half8*)(Ab + rf * 512 + lane * 8);
                        acc[rf][0] = __builtin_amdgcn_mfma_f32_16x16x32_f16(af, Breg[kc][0], acc[rf][0], 0, 0, 0);
                        acc[rf][1] = __builtin_amdgcn_mfma_f32_16x16x32_f16(af, Breg[kc][1], acc[rf][1], 0, 0, 0);
                    }
                }
            }
        }
    };

    if (pd) wait1(pd, pdt);                            // own h(l,t-1) + mbuf WAR
    if (l == 0) {
        stage_gemm(0, 10, false);
    } else {
        stage_gemm(8, 8, false);                       // own-recurrence half first
        if (pdlo) wait1(pdlo, pdlot);                  // lower layer h(l-1,t)
        stage_gemm(0, 8, xl);                          // lob half (coherent if cross-XCD)
    }
    __syncthreads();                                   // last MFMA reads done; zst aliases ring

    // ---- z write-all (one pass)
#pragma unroll
    for (int rf = 0; rf < 8; ++rf)
#pragma unroll
        for (int cf = 0; cf < 2; ++cf)
#pragma unroll
            for (int r = 0; r < 4; ++r)
                zst[(size_t)(rf * 16 + qd * 4 + r) * ZS + g * 64 + hh * 32 + cf * 16 + ln]
                    = acc[rf][cf][r];
    __syncthreads();

    // ---- elementwise: thread owns (row, 16 cols)
    const int row = tid >> 2, c0 = (tid & 3) * 16;
    const float* zrow = zst + (size_t)row * ZS;
    union { _Float16 h[16]; uint4 v[2]; } pk;
#pragma unroll
    for (int q = 0; q < 4; ++q) {
        const int o = q * 4;
        float4 zi = *(const float4*)(zrow + c0 + o);
        float4 zj = *(const float4*)(zrow + 64 + c0 + o);
        float4 zf = *(const float4*)(zrow + 128 + c0 + o);
        float4 zo = *(const float4*)(zrow + 192 + c0 + o);
        float4 bi = *(const float4*)(bst + c0 + o);
        float4 bj = *(const float4*)(bst + 64 + c0 + o);
        float4 bf = *(const float4*)(bst + 128 + c0 + o);
        float4 bo = *(const float4*)(bst + 192 + c0 + o);
        float cn0 = sigm(zf.x + bf.x) * c[o + 0] + sigm(zi.x + bi.x) * tanh_fast(zj.x + bj.x);
        float cn1 = sigm(zf.y + bf.y) * c[o + 1] + sigm(zi.y + bi.y) * tanh_fast(zj.y + bj.y);
        float cn2 = sigm(zf.z + bf.z) * c[o + 2] + sigm(zi.z + bi.z) * tanh_fast(zj.z + bj.z);
        float cn3 = sigm(zf.w + bf.w) * c[o + 3] + sigm(zi.w + bi.w) * tanh_fast(zj.w + bj.w);
        c[o + 0] = cn0; c[o + 1] = cn1; c[o + 2] = cn2; c[o + 3] = cn3;
        pk.h[o + 0] = (_Float16)(sigm(zo.x + bo.x) * tanh_fast(cn0));
        pk.h[o + 1] = (_Float16)(sigm(zo.y + bo.y) * tanh_fast(cn1));
        pk.h[o + 2] = (_Float16)(sigm(zo.z + bo.z) * tanh_fast(cn2));
        pk.h[o + 3] = (_Float16)(sigm(zo.w + bo.w) * tanh_fast(cn3));
    }
    _Float16* mb = mbuf + ((size_t)l * Bdim + b0r + row) * Hdim + h0 + c0;
    *(uint4*)mb       = pk.v[0];
    *(uint4*)(mb + 8) = pk.v[1];
}

// ---------------- proj step (R6 body, unchanged) ----------------
__device__ __forceinline__ void proj_step(
    int l, int b0r, int cq, const half8 (&Preg)[24],
    const _Float16* __restrict__ mbuf, _Float16* __restrict__ h16,
    _Float16* __restrict__ AstA, _Float16* __restrict__ AstB, int tid, bool xstore)
{
    const int wv = tid >> 6, lane = tid & 63, qd = lane >> 4, ln = lane & 15;
    const int rh = wv >> 2, cgi = wv & 3;
    const int rowg = b0r + wv * 16 + ln;
    const _Float16* mrow = mbuf + ((size_t)l * Bdim + rowg) * Hdim + qd * 8;
    _Float16* wA = AstA + wv * 512 + lane * 8;
    _Float16* wB = AstB + wv * 512 + lane * 8;

    floatx4 pacc[4];
    const floatx4 fz = {0.f, 0.f, 0.f, 0.f};
#pragma unroll
    for (int i = 0; i < 4; ++i) pacc[i] = fz;

    uint4 p0 = *(const uint4*)(mrow);
    uint4 p1 = *(const uint4*)(mrow + 32);
    uint4 p2 = *(const uint4*)(mrow + 64);
    uint4 p3 = *(const uint4*)(mrow + 96);
#pragma unroll
    for (int ch = 0; ch < 6; ++ch) {
        _Float16* W = (ch & 1) ? wB : wA;
        const _Float16* R = (ch & 1) ? AstB : AstA;
        *(uint4*)(W)                      = p0;
        *(uint4*)(W + (size_t)1 * 4096)   = p1;
        *(uint4*)(W + (size_t)2 * 4096)   = p2;
        *(uint4*)(W + (size_t)3 * 4096)   = p3;
        if (ch < 5) {
            p0 = *(const uint4*)(mrow + (4 * ch + 4) * 32);
            p1 = *(const uint4*)(mrow + (4 * ch + 5) * 32);
            p2 = *(const uint4*)(mrow + (4 * ch + 6) * 32);
            p3 = *(const uint4*)(mrow + (4 * ch + 7) * 32);
        }
        __syncthreads();                  // chunk staged; dbuf WAR covered
#pragma unroll
        for (int kk = 0; kk < 4; ++kk) {
            const _Float16* Ab = R + (size_t)kk * 4096;
#pragma unroll
            for (int rfl = 0; rfl < 4; ++rfl) {
                half8 af = *(const half8*)(Ab + (rh * 4 + rfl) * 512 + lane * 8);
                pacc[rfl] = __builtin_amdgcn_mfma_f32_16x16x32_f16(af, Preg[ch * 4 + kk], pacc[rfl], 0, 0, 0);
            }
        }
    }

    if (xstore) {
#pragma unroll
        for (int rfl = 0; rfl < 4; ++rfl)
#pragma unroll
            for (int r = 0; r < 4; ++r) {
                int row = b0r + (rh * 4 + rfl) * 16 + qd * 4 + r;
                st_coh16b(h16 + ((size_t)l * Bdim + row) * PJdim + cq * 64 + cgi * 16 + ln,
                          (_Float16)pacc[rfl][r]);
            }
    } else {
#pragma unroll
        for (int rfl = 0; rfl < 4; ++rfl)
#pragma unroll
            for (int r = 0; r < 4; ++r) {
                int row = b0r + (rh * 4 + rfl) * 16 + qd * 4 + r;
                h16[((size_t)l * Bdim + row) * PJdim + cq * 64 + cgi * 16 + ln] = (_Float16)pacc[rfl][r];
            }
    }
}

__device__ __forceinline__ void load_Breg(const _Float16* __restrict__ Wfrag, int l, int ht,
                                          int wv, int lane, half8 (&Breg)[16][2])
{
    const int g = wv >> 1, hh = wv & 1;
    const _Float16* wslab = Wfrag + ((size_t)(l * 12 + ht)) * 131072;
#pragma unroll
    for (int kc = 0; kc < 16; ++kc)
#pragma unroll
        for (int cf = 0; cf < 2; ++cf)
            Breg[kc][cf] = *(const half8*)(wslab + kc * 8192 + g * 2048 + (hh * 2 + cf) * 512 + lane * 8);
}

__device__ __forceinline__ void load_Preg(const _Float16* __restrict__ Pfrag, int l, int cq,
                                          int wv, int lane, half8 (&Preg)[24])
{
    const int cgi = wv & 3;
    const _Float16* pslab = Pfrag + (size_t)l * 196608 + (size_t)cq * 49152;
#pragma unroll
    for (int kc = 0; kc < 24; ++kc)
        Preg[kc] = *(const half8*)(pslab + kc * 2048 + cgi * 512 + lane * 8);
}

__device__ __forceinline__ void load_bst(const float* __restrict__ bias, int h0, int tid,
                                         float* __restrict__ bst)
{
    if (tid < 256) {
        int gg = tid >> 6, u = tid & 63;
        bst[tid] = bias[gg * Hdim + h0 + u] + ((gg == 2) ? 1.0f : 0.0f);  // forget bias folded
    }
}

__device__ __forceinline__ void finalize_row(const _Float16* __restrict__ h16,
                                             float* __restrict__ out, int row, int lane)
{
    const _Float16* e = h16 + ((size_t)2 * Bdim + row) * PJdim + lane * 4;
    float v0 = (float)e[0], v1 = (float)e[1], v2 = (float)e[2], v3 = (float)e[3];
    float ss = v0 * v0 + v1 * v1 + v2 * v2 + v3 * v3;
#pragma unroll
    for (int o = 32; o > 0; o >>= 1) ss += __shfl_xor(ss, o, 64);
    float rs = rsqrtf(fmaxf(ss, 1e-12f));
    float4 o4; o4.x = v0 * rs; o4.y = v1 * rs; o4.z = v2 * rs; o4.w = v3 * rs;
    *(float4*)(out + (size_t)row * PJdim + lane * 4) = o4;
}

// ---------------- persistent kernel (R6 structure; L1-only acquire) ----------------
// Hazard/DAG audit identical to R3/R6. Coherence audit:
//  same-XCD edges (mbuf, own h16, h16 odd->even+1 within XCD pair): producer
//    write-through stores -> shared L2 fresh; consumer L1 inv'd at wait -> OK.
//  cross-XCD edges (h16 of odd gids {1,3,7,9,13} -> even-gid l>0 consumers):
//    producer st_coh16b (LLC); consumer ld_coh16 (LLC, bypasses stale L2) -> OK.
__global__ __launch_bounds__(512)
void lstm_persist(const _Float16* __restrict__ x16, const _Float16* __restrict__ Wfrag,
                  const _Float16* __restrict__ Pfrag,
                  const float* __restrict__ bias0, const float* __restrict__ bias1,
                  const float* __restrict__ bias2,
                  _Float16* __restrict__ h16, _Float16* __restrict__ mbuf,
                  const _Float16* __restrict__ zerop, float* __restrict__ out,
                  unsigned* __restrict__ flags)
{
    __shared__ __align__(16) char LDSRAW[133120];
    _Float16* Ast  = (_Float16*)LDSRAW;
    float*    zst  = (float*)LDSRAW;
    float*    bst  = (float*)(LDSRAW + 132096);

    const int tid = threadIdx.x, bid = blockIdx.x;
    const int wv = tid >> 6, lane = tid & 63;

    // XCD-grouped role mapping: gid lives on XCD gid>>1 (assuming bid%8=XCD)
    const int xcd = bid & 7, slot = bid >> 3;
    const int gid = xcd * 2 + (slot >> 4);
    const int rr  = slot & 15;
    if (gid >= 15) return;                              // 16 idle blocks exit
    const int bt2 = gid / 3, l = gid % 3;
    const int b0r = bt2 * 128;

    unsigned* gd = flags + (size_t)gid * 64;            // 256B-spread counters
    unsigned* pd = gd + 32;

    if (rr < 12) {                                      // ---- gate block ----
        const int ht = rr, h0 = ht * 64;
        const bool xl = ((gid & 1) == 0) && (l > 0);    // lob producer on other XCD
        half8 Breg[16][2];
        load_Breg(Wfrag, l, ht, wv, lane, Breg);
        load_bst((l == 0) ? bias0 : (l == 1) ? bias1 : bias2, h0, tid, bst);
        float c[16];
#pragma unroll
        for (int u = 0; u < 16; ++u) c[u] = 0.f;
        unsigned* pd_lo = (l > 0) ? flags + (size_t)(gid - 1) * 64 + 32 : nullptr;
        for (int t = 0; t < Tdim; ++t) {
            gate_step(l, b0r, h0, t, xl, Breg, c, x16, h16, zerop, mbuf,
                      Ast, zst, bst,
                      pd, 4u * (unsigned)t,
                      pd_lo, (l > 0) ? 4u * (unsigned)(t + 1) : 0u, tid);
            pipe_sig(gd);
        }
        if (l == 2 && rr < 8) {                         // finalize: 8 blocks x 16 rows per gid
            wait1(pd, 4u * (unsigned)Tdim);             // same-XCD producer; L1 inv suffices
            int row0 = b0r + rr * 16 + wv * 2;
            finalize_row(h16, out, row0, lane);
            finalize_row(h16, out, row0 + 1, lane);
        }
    } else {                                            // ---- proj block ----
        const int cq = rr - 12;
        const bool xstore = ((gid & 1) == 1) && (gid + 1 < 15) && ((gid + 1) % 3 != 0);
        half8 Preg[24];
        load_Preg(Pfrag, l, cq, wv, lane, Preg);
        unsigned* gd_hi = (l < 2) ? flags + (size_t)(gid + 1) * 64 : nullptr;
        for (int t = 0; t < Tdim; ++t) {
            pipe_wait(gd, 12u * (unsigned)(t + 1), gd_hi, (l < 2) ? 12u * (unsigned)t : 0u);
            proj_step(l, b0r, cq, Preg, mbuf, h16,
                      Ast, (_Float16*)(LDSRAW + 32768), tid, xstore);
            pipe_sig(pd);
        }
    }
}

// ---------------- fallback: per-step kernels, c-state in global ----------------
__global__ __launch_bounds__(512)
void gate_fb(const _Float16* __restrict__ x16, const _Float16* __restrict__ Wfrag,
             const float* __restrict__ bias0, const float* __restrict__ bias1,
             const float* __restrict__ bias2,
             _Float16* __restrict__ h16, _Float16* __restrict__ mbuf,
             const _Float16* __restrict__ zerop, float* __restrict__ cfb, int s)
{
    __shared__ __align__(16) char LDSRAW[133120];
    _Float16* Ast  = (_Float16*)LDSRAW;
    float*    zst  = (float*)LDSRAW;
    float*    bst  = (float*)(LDSRAW + 132096);
    const int tid = threadIdx.x, bid = blockIdx.x;
    const int ht = bid % 12, z = bid / 12, l = z % 3, bt2 = z / 3;
    const int t = s - l;
    if (t < 0 || t >= Tdim) return;
    const int wv = tid >> 6, lane = tid & 63;
    const int b0r = bt2 * 128, h0 = ht * 64;
    half8 Breg[16][2];
    load_Breg(Wfrag, l, ht, wv, lane, Breg);
    load_bst((l == 0) ? bias0 : (l == 1) ? bias1 : bias2, h0, tid, bst);
    __syncthreads();
    const int row = tid >> 2, c0 = (tid & 3) * 16;
    float c[16];
#pragma unroll
    for (int u = 0; u < 16; ++u)
        c[u] = cfb[((size_t)l * Bdim + b0r + row) * Hdim + h0 + c0 + u];
    gate_step(l, b0r, h0, t, false, Breg, c, x16, h16, zerop, mbuf, Ast, zst, bst,
              nullptr, 0u, nullptr, 0u, tid);
#pragma unroll
    for (int u = 0; u < 16; ++u)
        cfb[((size_t)l * Bdim + b0r + row) * Hdim + h0 + c0 + u] = c[u];
}

__global__ __launch_bounds__(512)
void proj_fb(const _Float16* __restrict__ Pfrag, const _Float16* __restrict__ mbuf,
             _Float16* __restrict__ h16, int s)
{
    __shared__ __align__(16) char LDSRAW[65536];
    const int tid = threadIdx.x, bid = blockIdx.x;
    const int cq = bid & 3, z = bid >> 2, l = z % 3, bt2 = z / 3;
    const int tp = s - l;
    if (tp < 0 || tp >= Tdim) return;
    const int wv = tid >> 6, lane = tid & 63;
    half8 Preg[24];
    load_Preg(Pfrag, l, cq, wv, lane, Preg);
    proj_step(l, bt2 * 128, cq, Preg, mbuf, h16,
              (_Float16*)LDSRAW, (_Float16*)(LDSRAW + 32768), tid, false);
}

__global__ __launch_bounds__(512)
void fin_fb(const _Float16* __restrict__ h16, float* __restrict__ out)
{
    int row = blockIdx.x * 8 + (threadIdx.x >> 6);
    finalize_row(h16, out, row, threadIdx.x & 63);
}

extern "C" void kernel_launch(void* const* d_in, const int* in_sizes, int n_in,
                              void* d_out, int out_size, void* d_ws, size_t ws_size,
                              hipStream_t stream)
{
    (void)in_sizes; (void)n_in; (void)out_size; (void)ws_size;
    const float* x  = (const float*)d_in[0];
    const float* W0 = (const float*)d_in[1];
    const float* b0 = (const float*)d_in[2];
    const float* P0 = (const float*)d_in[3];
    const float* W1 = (const float*)d_in[4];
    const float* b1 = (const float*)d_in[5];
    const float* P1 = (const float*)d_in[6];
    const float* W2 = (const float*)d_in[7];
    const float* b2 = (const float*)d_in[8];
    const float* P2 = (const float*)d_in[9];

    char* ws = (char*)d_ws;
    _Float16* h16   = (_Float16*)(ws);
    _Float16* zerop = (_Float16*)(ws + ZP_OFF);
    _Float16* mbuf  = (_Float16*)(ws + MB_OFF);
    _Float16* x16   = (_Float16*)(ws + X_OFF);
    _Float16* Wfrag = (_Float16*)(ws + W_OFF);
    _Float16* Pfrag = (_Float16*)(ws + P_OFF);
    float*    cfb   = (float*)(ws + C_OFF);
    unsigned* flags = (unsigned*)(ws + C_OFF);   // coop path only; aliases cfb (fallback-only)
    float*    outp  = (float*)d_out;

    // zero h state + zero page (+ fallback c / pipe flags — same region)
    hipMemsetAsync(ws, 0, ZP_OFF + 256, stream);
    hipMemsetAsync(cfb, 0, C_BYTES, stream);

    {
        constexpr size_t total = W_HALFS + P_HALFS + X_HALFS;
        int grid = (int)((total + 255) / 256);
        repack_kernel<<<grid, 256, 0, stream>>>(x, W0, W1, W2, P0, P1, P2, Wfrag, Pfrag, x16);
    }

    int occ = 0;
    hipError_t oe = hipOccupancyMaxActiveBlocksPerMultiprocessor(&occ, lstm_persist, 512, 0);
    bool coop = (oe == hipSuccess && occ >= 1);
    if (coop) {
        void* args[] = { (void*)&x16, (void*)&Wfrag, (void*)&Pfrag,
                         (void*)&b0, (void*)&b1, (void*)&b2,
                         (void*)&h16, (void*)&mbuf, (void*)&zerop, (void*)&outp,
                         (void*)&flags };
        hipError_t le = hipLaunchCooperativeKernel((const void*)lstm_persist,
                                                   dim3(256), dim3(512), args, 0, stream);
        if (le != hipSuccess) { (void)hipGetLastError(); coop = false; }
    }
    if (!coop) {
        for (int s = 0; s < NSTEP; ++s) {
            gate_fb<<<180, 512, 0, stream>>>(x16, Wfrag, b0, b1, b2, h16, mbuf, zerop, cfb, s);
            proj_fb<<<60, 512, 0, stream>>>(Pfrag, mbuf, h16, s);
        }
        fin_fb<<<80, 512, 0, stream>>>(h16, outp);
    }
}